// Round 9
// baseline (710.873 us; speedup 1.0000x reference)
//
#include <hip/hip_runtime.h>
#include <hip/hip_bf16.h>

#define NN 50000
#define EE 500000
#define GG 64
#define HIDD 128
#define HEADS 8
#define DHH 16
#define NBLK ((NN + 255) / 256)   // 196
#define RTILES 3128               // ceil(50000/16) rowtiles of 16
#define GEMM_GRID 391             // ceil(50000/128)

typedef __bf16 bf16x8 __attribute__((ext_vector_type(8)));
typedef float f32x4 __attribute__((ext_vector_type(4)));

// 8-lane sum reduce, pure DPP: quad xor1, quad xor2, cross-quad (row_half_mirror).
__device__ inline float rowsum8(float y) {
  int t;
  t = __builtin_amdgcn_mov_dpp(__float_as_int(y), 0xB1, 0xF, 0xF, true);  y += __int_as_float(t);
  t = __builtin_amdgcn_mov_dpp(__float_as_int(y), 0x4E, 0xF, 0xF, true);  y += __int_as_float(t);
  t = __builtin_amdgcn_mov_dpp(__float_as_int(y), 0x141, 0xF, 0xF, true); y += __int_as_float(t);
  return y;
}

__device__ inline float2 unpk2(unsigned u) {
  return make_float2(__uint_as_float(u << 16), __uint_as_float(u & 0xFFFF0000u));
}

// blocked bf16 fragment offset for element (row, 8-col-group kc)
__device__ inline int frag_off(int row, int kc) {
  return (row >> 4) * 2048 + (kc >> 2) * 512 + ((row & 15) + (kc & 3) * 16) * 8;
}

// ---------------- degree ----------------
__global__ void deg_kernel(const int* __restrict__ src, const int* __restrict__ dst,
                           int* __restrict__ outdeg, int* __restrict__ indeg) {
  int i = blockIdx.x * blockDim.x + threadIdx.x;
  int stride = gridDim.x * blockDim.x;
  for (; i < EE; i += stride) {
    atomicAdd(&outdeg[src[i]], 1);
    atomicAdd(&indeg[dst[i]], 1);
  }
}

__global__ void norm_kernel(const int* __restrict__ outdeg, float* __restrict__ ns) {
  int i = blockIdx.x * blockDim.x + threadIdx.x;
  if (i < NN) ns[i] = rsqrtf((float)max(outdeg[i], 1));
}

// ---------------- hierarchical exclusive scan ----------------
__global__ __launch_bounds__(256) void scan1_kernel(const int* __restrict__ deg,
                                                    int* __restrict__ excl,
                                                    int* __restrict__ bsum) {
  __shared__ int buf[256];
  int t = threadIdx.x;
  int idx = blockIdx.x * 256 + t;
  int v = (idx < NN) ? deg[idx] : 0;
  buf[t] = v;
  __syncthreads();
#pragma unroll
  for (int off = 1; off < 256; off <<= 1) {
    int tmp = (t >= off) ? buf[t - off] : 0;
    __syncthreads();
    buf[t] += tmp;
    __syncthreads();
  }
  if (idx < NN) excl[idx] = buf[t] - v;
  if (t == 255) bsum[blockIdx.x] = buf[255];
}

__global__ __launch_bounds__(256) void scan2_kernel(int* __restrict__ bsum) {
  __shared__ int buf[256];
  int t = threadIdx.x;
  int v = (t < NBLK) ? bsum[t] : 0;
  buf[t] = v;
  __syncthreads();
#pragma unroll
  for (int off = 1; off < 256; off <<= 1) {
    int tmp = (t >= off) ? buf[t - off] : 0;
    __syncthreads();
    buf[t] += tmp;
    __syncthreads();
  }
  if (t < NBLK) bsum[t] = buf[t] - v;
}

__global__ __launch_bounds__(256) void scan3_kernel(int* __restrict__ excl,
                                                    const int* __restrict__ bsum,
                                                    int* __restrict__ cursor) {
  int idx = blockIdx.x * 256 + threadIdx.x;
  if (idx < NN) {
    int v = excl[idx] + bsum[blockIdx.x];
    excl[idx] = v;
    cursor[idx] = v;
  }
}

__global__ void bin_kernel(const int* __restrict__ src, const int* __restrict__ dst,
                           int* __restrict__ cursor, int* __restrict__ csr_src) {
  int i = blockIdx.x * blockDim.x + threadIdx.x;
  int stride = gridDim.x * blockDim.x;
  for (; i < EE; i += stride) {
    int pos = atomicAdd(&cursor[dst[i]], 1);
    csr_src[pos] = src[i];
  }
}

// ---------------- bf16 hi/lo weight split (transposed, k-blocked, pre-swizzled) ----------------
__global__ __launch_bounds__(256) void split_w_kernel(
    const float* __restrict__ W_gc1, const float* __restrict__ W_gc2,
    const float* __restrict__ W_src, const float* __restrict__ W_dst,
    __bf16* __restrict__ Wblk)
{
  int tid = blockIdx.x * 256 + threadIdx.x;   // 8 * 16384
  int m = tid >> 14;
  int kn = tid & 16383;
  int k = kn >> 7, n = kn & 127;
  const float* Wm = (m == 0) ? W_gc1 : (m == 1) ? W_gc2
                   : (m < 5) ? (W_src + (m - 2) * 16384) : (W_dst + (m - 5) * 16384);
  float v = Wm[kn];
  __bf16 h = (__bf16)v;
  __bf16 l = (__bf16)(v - (float)h);
  int ks = k >> 5;
  int L = n * 32 + ((k >> 3) & 3) * 8 + (k & 7);
  int swz = L ^ ((n & 7) << 3);
  __bf16* dstp = Wblk + m * 32768 + ks * 8192;
  dstp[swz] = h;
  dstp[4096 + swz] = l;
}

// ---------------- bf16 hi/lo input split (feature only) ----------------
__global__ __launch_bounds__(256) void split_h_kernel(
    const float* __restrict__ X, const float* __restrict__ scale,
    __bf16* __restrict__ Ah, __bf16* __restrict__ Al)
{
  int tid = blockIdx.x * 256 + threadIdx.x;   // RTILES*16*16
  int row = tid >> 4, kc = tid & 15;
  float v[8];
  if (row < NN) {
    const float4* p = (const float4*)(X + row * 128 + kc * 8);
    float4 a = p[0], b = p[1];
    float s = scale ? scale[row] : 1.f;
    v[0] = a.x * s; v[1] = a.y * s; v[2] = a.z * s; v[3] = a.w * s;
    v[4] = b.x * s; v[5] = b.y * s; v[6] = b.z * s; v[7] = b.w * s;
  } else {
#pragma unroll
    for (int i = 0; i < 8; ++i) v[i] = 0.f;
  }
  bf16x8 hi, lo;
#pragma unroll
  for (int i = 0; i < 8; ++i) {
    __bf16 h = (__bf16)v[i];
    hi[i] = h;
    lo[i] = (__bf16)(v[i] - (float)h);
  }
  int off = frag_off(row, kc);
  *(bf16x8*)(Ah + off) = hi;
  *(bf16x8*)(Al + off) = lo;
}

// ---------------- bf16x3 MFMA GEMM core ----------------
__device__ inline void gemm_body(
    const __bf16* __restrict__ Ah, const __bf16* __restrict__ Al,
    const __bf16* __restrict__ Wmat, const float* __restrict__ bias,
    __bf16* __restrict__ outb, int bx, __bf16* wt)
{
  int tid = threadIdx.x;
  int wid = tid >> 6, lane = tid & 63;
  int wr = wid >> 1, wc = wid & 1;
  int l15 = lane & 15, l4 = lane >> 4;
  f32x4 acc[4][4];
#pragma unroll
  for (int a = 0; a < 4; ++a)
#pragma unroll
    for (int b = 0; b < 4; ++b) acc[a][b] = (f32x4){0.f, 0.f, 0.f, 0.f};
  int rowtile0 = bx * 8 + wr * 4;

  for (int ks = 0; ks < 4; ++ks) {
    {
      const bf16x8* g = (const bf16x8*)(Wmat + ks * 8192);
      bf16x8* l = (bf16x8*)wt;
      l[tid]       = g[tid];
      l[tid + 256] = g[tid + 256];
      l[tid + 512] = g[tid + 512];
      l[tid + 768] = g[tid + 768];
    }
    bf16x8 ah[4], al[4];
#pragma unroll
    for (int rt = 0; rt < 4; ++rt) {
      int off = (rowtile0 + rt) * 2048 + ks * 512 + lane * 8;
      ah[rt] = *(const bf16x8*)(Ah + off);
      al[rt] = *(const bf16x8*)(Al + off);
    }
    __syncthreads();
#pragma unroll
    for (int ct = 0; ct < 4; ++ct) {
      int n = wc * 64 + ct * 16 + l15;
      int ei = (n * 32 + l4 * 8) ^ ((n & 7) << 3);
      bf16x8 bh = *(const bf16x8*)(wt + ei);
      bf16x8 bl = *(const bf16x8*)(wt + 4096 + ei);
#pragma unroll
      for (int rt = 0; rt < 4; ++rt) {
        acc[rt][ct] = __builtin_amdgcn_mfma_f32_16x16x32_bf16(ah[rt], bh, acc[rt][ct], 0, 0, 0);
        acc[rt][ct] = __builtin_amdgcn_mfma_f32_16x16x32_bf16(ah[rt], bl, acc[rt][ct], 0, 0, 0);
        acc[rt][ct] = __builtin_amdgcn_mfma_f32_16x16x32_bf16(al[rt], bh, acc[rt][ct], 0, 0, 0);
      }
    }
    __syncthreads();
  }
  int rowbase = bx * 128 + wr * 64;
#pragma unroll
  for (int ct = 0; ct < 4; ++ct) {
    int col = wc * 64 + ct * 16 + l15;
    float b = bias ? bias[col] : 0.f;
#pragma unroll
    for (int rt = 0; rt < 4; ++rt) {
#pragma unroll
      for (int r = 0; r < 4; ++r) {
        int row = rowbase + rt * 16 + l4 * 4 + r;
        if (row < NN) outb[row * 128 + col] = (__bf16)(acc[rt][ct][r] + b);
      }
    }
  }
}

__global__ __launch_bounds__(256) void gemm_mfma(
    const __bf16* __restrict__ Ah, const __bf16* __restrict__ Al,
    const __bf16* __restrict__ Wmat, const float* __restrict__ bias,
    __bf16* __restrict__ outb)
{
  __shared__ __bf16 wt[8192];
  gemm_body(Ah, Al, Wmat, bias, outb, blockIdx.x, wt);
}

// fs and fd GEMMs of one GAT layer in a single dispatch (grid = 2*GEMM_GRID)
__global__ __launch_bounds__(256) void gemm_dual(
    const __bf16* __restrict__ Ah, const __bf16* __restrict__ Al,
    const __bf16* __restrict__ W0, const __bf16* __restrict__ W1,
    const float* __restrict__ bias0, const float* __restrict__ bias1,
    __bf16* __restrict__ out0, __bf16* __restrict__ out1)
{
  __shared__ __bf16 wt[8192];
  int which = (blockIdx.x >= GEMM_GRID);
  int bx = blockIdx.x - (which ? GEMM_GRID : 0);
  gemm_body(Ah, Al, which ? W1 : W0, which ? bias1 : bias0,
            which ? out1 : out0, bx, wt);
}

// ---------------- GraphConv aggregation: bf16 gather, 64 thr/node, x4 unroll ----------------
__global__ __launch_bounds__(64) void gc_agg_kernel(
    const __bf16* __restrict__ mb, const int* __restrict__ rowoff,
    const int* __restrict__ indeg, const int* __restrict__ csr_src,
    const float2* __restrict__ bias2, const float* __restrict__ nsrow,
    __bf16* __restrict__ Ah, __bf16* __restrict__ Al)   // split out (always)
{
  __shared__ float buf[128];
  int d = blockIdx.x, c = threadIdx.x;
  int ro = rowoff[d], dg = indeg[d];
  float2 a0 = {0.f, 0.f}, a1 = {0.f, 0.f}, a2 = {0.f, 0.f}, a3 = {0.f, 0.f};
  int j = 0;
  for (; j + 4 <= dg; j += 4) {
    int s0 = csr_src[ro + j], s1 = csr_src[ro + j + 1];
    int s2 = csr_src[ro + j + 2], s3 = csr_src[ro + j + 3];
    float2 v0 = unpk2(*(const unsigned*)(mb + s0 * 128 + 2 * c));
    float2 v1 = unpk2(*(const unsigned*)(mb + s1 * 128 + 2 * c));
    float2 v2 = unpk2(*(const unsigned*)(mb + s2 * 128 + 2 * c));
    float2 v3 = unpk2(*(const unsigned*)(mb + s3 * 128 + 2 * c));
    a0.x += v0.x; a0.y += v0.y; a1.x += v1.x; a1.y += v1.y;
    a2.x += v2.x; a2.y += v2.y; a3.x += v3.x; a3.y += v3.y;
  }
  for (; j < dg; ++j) {
    float2 v = unpk2(*(const unsigned*)(mb + csr_src[ro + j] * 128 + 2 * c));
    a0.x += v.x; a0.y += v.y;
  }
  float accx = (a0.x + a1.x) + (a2.x + a3.x);
  float accy = (a0.y + a1.y) + (a2.y + a3.y);
  float ndv = rsqrtf((float)max(dg, 1));
  float2 b = bias2[c];
  float vx = fmaxf(accx * ndv + b.x, 0.f);
  float vy = fmaxf(accy * ndv + b.y, 0.f);
  float s = nsrow ? nsrow[d] : 1.f;
  ((float2*)buf)[c] = make_float2(vx * s, vy * s);
  __syncthreads();
  if (c < 32) {
    int kc = c & 15;
    int off = frag_off(d, kc);
    bf16x8 pk;
    if (c < 16) {
#pragma unroll
      for (int i = 0; i < 8; ++i) pk[i] = (__bf16)buf[kc * 8 + i];
      *(bf16x8*)(Ah + off) = pk;
    } else {
#pragma unroll
      for (int i = 0; i < 8; ++i) {
        float x = buf[kc * 8 + i];
        __bf16 hh = (__bf16)x;
        pk[i] = (__bf16)(x - (float)hh);
      }
      *(bf16x8*)(Al + off) = pk;
    }
  }
}

// ---------------- Fused GATv2: 4-way online softmax; h lives in the hi/lo split ----------------
// Residual h is read from Ah+Al (exact to 2^-17); result is written back as a new
// split (non-last layers) or as fp32 h0 for pooling (last layer).
__global__ __launch_bounds__(64) void gat_node_kernel(
    const __bf16* __restrict__ fsb,   // [N][128] bf16
    const __bf16* __restrict__ fdb,   // [N][128] bf16
    const float* __restrict__ attn,
    const int* __restrict__ rowoff, const int* __restrict__ indeg,
    const int* __restrict__ csr_src,
    __bf16* __restrict__ Ah, __bf16* __restrict__ Al,   // in: residual; out: next split
    float2* __restrict__ out2)        // non-null = last layer: write fp32 h, skip split
{
  __shared__ float buf[128];
  int d = blockIdx.x, c = threadIdx.x;
  int ro = rowoff[d], dg = indeg[d];
  float2 fdp = unpk2(*(const unsigned*)(fdb + d * 128 + 2 * c));
  float2 ap = ((const float2*)attn)[c];
  float mA = -INFINITY, sA = 0.f; float2 aA = {0.f, 0.f};
  float mB = -INFINITY, sB = 0.f; float2 aB = {0.f, 0.f};
  float mC = -INFINITY, sC = 0.f; float2 aC = {0.f, 0.f};
  float mD = -INFINITY, sD = 0.f; float2 aD = {0.f, 0.f};
  int j = 0;
  for (; j + 4 <= dg; j += 4) {
    int s0 = csr_src[ro + j],     s1 = csr_src[ro + j + 1];
    int s2 = csr_src[ro + j + 2], s3 = csr_src[ro + j + 3];
    float2 f0 = unpk2(*(const unsigned*)(fsb + s0 * 128 + 2 * c));
    float2 f1 = unpk2(*(const unsigned*)(fsb + s1 * 128 + 2 * c));
    float2 f2 = unpk2(*(const unsigned*)(fsb + s2 * 128 + 2 * c));
    float2 f3 = unpk2(*(const unsigned*)(fsb + s3 * 128 + 2 * c));
    float x0 = f0.x + fdp.x; x0 = fmaxf(x0, 0.f) + 0.2f * fminf(x0, 0.f);
    float z0 = f0.y + fdp.y; z0 = fmaxf(z0, 0.f) + 0.2f * fminf(z0, 0.f);
    float x1 = f1.x + fdp.x; x1 = fmaxf(x1, 0.f) + 0.2f * fminf(x1, 0.f);
    float z1 = f1.y + fdp.y; z1 = fmaxf(z1, 0.f) + 0.2f * fminf(z1, 0.f);
    float x2 = f2.x + fdp.x; x2 = fmaxf(x2, 0.f) + 0.2f * fminf(x2, 0.f);
    float z2 = f2.y + fdp.y; z2 = fmaxf(z2, 0.f) + 0.2f * fminf(z2, 0.f);
    float x3 = f3.x + fdp.x; x3 = fmaxf(x3, 0.f) + 0.2f * fminf(x3, 0.f);
    float z3 = f3.y + fdp.y; z3 = fmaxf(z3, 0.f) + 0.2f * fminf(z3, 0.f);
    float y0 = rowsum8(ap.x * x0 + ap.y * z0);
    float y1 = rowsum8(ap.x * x1 + ap.y * z1);
    float y2 = rowsum8(ap.x * x2 + ap.y * z2);
    float y3 = rowsum8(ap.x * x3 + ap.y * z3);
    float nm, sc, p;
    nm = fmaxf(mA, y0); sc = __expf(mA - nm); p = __expf(y0 - nm);
    sA = sA * sc + p; aA.x = aA.x * sc + p * f0.x; aA.y = aA.y * sc + p * f0.y; mA = nm;
    nm = fmaxf(mB, y1); sc = __expf(mB - nm); p = __expf(y1 - nm);
    sB = sB * sc + p; aB.x = aB.x * sc + p * f1.x; aB.y = aB.y * sc + p * f1.y; mB = nm;
    nm = fmaxf(mC, y2); sc = __expf(mC - nm); p = __expf(y2 - nm);
    sC = sC * sc + p; aC.x = aC.x * sc + p * f2.x; aC.y = aC.y * sc + p * f2.y; mC = nm;
    nm = fmaxf(mD, y3); sc = __expf(mD - nm); p = __expf(y3 - nm);
    sD = sD * sc + p; aD.x = aD.x * sc + p * f3.x; aD.y = aD.y * sc + p * f3.y; mD = nm;
  }
  for (; j < dg; ++j) {
    int s0 = csr_src[ro + j];
    float2 f0 = unpk2(*(const unsigned*)(fsb + s0 * 128 + 2 * c));
    float x0 = f0.x + fdp.x; x0 = fmaxf(x0, 0.f) + 0.2f * fminf(x0, 0.f);
    float z0 = f0.y + fdp.y; z0 = fmaxf(z0, 0.f) + 0.2f * fminf(z0, 0.f);
    float y0 = rowsum8(ap.x * x0 + ap.y * z0);
    float nm = fmaxf(mA, y0);
    float sc = __expf(mA - nm), p = __expf(y0 - nm);
    sA = sA * sc + p; aA.x = aA.x * sc + p * f0.x; aA.y = aA.y * sc + p * f0.y; mA = nm;
  }
  // residual from split (hi + lo)
  int rbase = frag_off(d, c >> 2) + ((2 * c) & 7);
  float2 rh = unpk2(*(const unsigned*)(Ah + rbase));
  float2 rl = unpk2(*(const unsigned*)(Al + rbase));
  float ox = 0.f, oy = 0.f;
  if (dg > 0) {
    float M = fmaxf(fmaxf(mA, mB), fmaxf(mC, mD));
    float eA = __expf(mA - M), eB = __expf(mB - M);
    float eC = __expf(mC - M), eD = __expf(mD - M);
    float inv = 1.f / (sA * eA + sB * eB + sC * eC + sD * eD);
    ox = (aA.x * eA + aB.x * eB + aC.x * eC + aD.x * eD) * inv;
    oy = (aA.y * eA + aB.y * eB + aC.y * eC + aD.y * eD) * inv;
  }
  float vx = fmaxf(ox + (rh.x + rl.x), 0.f);
  float vy = fmaxf(oy + (rh.y + rl.y), 0.f);
  if (out2) {
    out2[d * 64 + c] = make_float2(vx, vy);
  } else {
    ((float2*)buf)[c] = make_float2(vx, vy);
    __syncthreads();
    if (c < 32) {
      int kc = c & 15;
      int off = frag_off(d, kc);
      bf16x8 pk;
      if (c < 16) {
#pragma unroll
        for (int i = 0; i < 8; ++i) pk[i] = (__bf16)buf[kc * 8 + i];
        *(bf16x8*)(Ah + off) = pk;
      } else {
#pragma unroll
        for (int i = 0; i < 8; ++i) {
          float x = buf[kc * 8 + i];
          __bf16 hh = (__bf16)x;
          pk[i] = (__bf16)(x - (float)hh);
        }
        *(bf16x8*)(Al + off) = pk;
      }
    }
  }
}

// ---------------- pooling (n2g sorted: per-graph range + few atomics) ----------------
__global__ __launch_bounds__(128) void pool_kernel(const float* __restrict__ h,
                                                   const int* __restrict__ n2g,
                                                   unsigned* __restrict__ hg)
{
  int g = blockIdx.x >> 3, chunk = blockIdx.x & 7, c = threadIdx.x;
  int lo = 0, hi = NN;
  while (lo < hi) { int mid = (lo + hi) >> 1; if (n2g[mid] < g) lo = mid + 1; else hi = mid; }
  int start = lo;
  hi = NN;
  while (lo < hi) { int mid = (lo + hi) >> 1; if (n2g[mid] < g + 1) lo = mid + 1; else hi = mid; }
  int end = lo;
  int len = end - start;
  int s = start + (int)(((long long)len * chunk) >> 3);
  int e = start + (int)(((long long)len * (chunk + 1)) >> 3);
  float m = 0.f;
  for (int r = s; r < e; ++r) m = fmaxf(m, h[r * 128 + c]);
  atomicMax(&hg[g * 128 + c], __float_as_uint(m));
}

__global__ __launch_bounds__(128) void mlp_kernel(
    const float* __restrict__ hg,
    const float* __restrict__ Wc1, const float* __restrict__ bc1,
    const float* __restrict__ Wc2, const float* __restrict__ bc2,
    const float* __restrict__ Wc3, const float* __restrict__ bc3,
    float* __restrict__ out)
{
  __shared__ float x[128], z1[128], z2[64];
  int g = blockIdx.x, t = threadIdx.x;
  x[t] = hg[g * 128 + t];
  __syncthreads();
  float acc = bc1[t];
  for (int k = 0; k < 128; ++k) acc += x[k] * Wc1[k * 128 + t];
  z1[t] = fmaxf(acc, 0.f);
  __syncthreads();
  if (t < 64) {
    float a2 = bc2[t];
    for (int k = 0; k < 128; ++k) a2 += z1[k] * Wc2[k * 64 + t];
    z2[t] = fmaxf(a2, 0.f);
  }
  __syncthreads();
#pragma unroll
  for (int p = 0; p < 2; ++p) {
    int c = t + p * 128;
    float a3 = bc3[c];
    for (int k = 0; k < 64; ++k) a3 += z2[k] * Wc3[k * 256 + c];
    out[g * 256 + c] = a3;
  }
}

// ---------------- launch ----------------
extern "C" void kernel_launch(void* const* d_in, const int* in_sizes, int n_in,
                              void* d_out, int out_size, void* d_ws, size_t ws_size,
                              hipStream_t stream)
{
  const float* feature = (const float*)d_in[0];
  const float* W_gc1 = (const float*)d_in[1];
  const float* b_gc1 = (const float*)d_in[2];
  const float* W_gc2 = (const float*)d_in[3];
  const float* b_gc2 = (const float*)d_in[4];
  const float* W_src = (const float*)d_in[5];
  const float* b_src = (const float*)d_in[6];
  const float* W_dst = (const float*)d_in[7];
  const float* b_dst = (const float*)d_in[8];
  const float* attn  = (const float*)d_in[9];
  const float* Wc1 = (const float*)d_in[10];
  const float* bc1 = (const float*)d_in[11];
  const float* Wc2 = (const float*)d_in[12];
  const float* bc2 = (const float*)d_in[13];
  const float* Wc3 = (const float*)d_in[14];
  const float* bc3 = (const float*)d_in[15];
  const int* src = (const int*)d_in[16];
  const int* dst = (const int*)d_in[17];
  const int* n2g = (const int*)d_in[18];

  char* base = (char*)d_ws;
  int* indeg  = (int*)base;            base += NN * sizeof(int);
  int* outdeg = (int*)base;            base += NN * sizeof(int);
  int* rowoff = (int*)base;            base += NN * sizeof(int);
  int* cursor = (int*)base;            base += NN * sizeof(int);
  int* bsum   = (int*)base;            base += 256 * sizeof(int);
  int* csr_src = (int*)base;           base += EE * sizeof(int);
  float* ns = (float*)base;            base += NN * sizeof(float);
  float* h0 = (float*)base;            base += (size_t)NN * HIDD * sizeof(float);
  __bf16* fsb = (__bf16*)base;         base += (size_t)NN * HIDD * sizeof(__bf16);
  __bf16* fdb = (__bf16*)base;         base += (size_t)NN * HIDD * sizeof(__bf16);
  __bf16* mb  = (__bf16*)base;         base += (size_t)NN * HIDD * sizeof(__bf16);
  __bf16* Ah = (__bf16*)base;          base += (size_t)RTILES * 2048 * sizeof(__bf16);
  __bf16* Al = (__bf16*)base;          base += (size_t)RTILES * 2048 * sizeof(__bf16);
  __bf16* Wblk = (__bf16*)base;        base += (size_t)8 * 32768 * sizeof(__bf16);
  float* hg = (float*)base;            base += GG * HIDD * sizeof(float);

  // degrees, norms, CSR
  hipMemsetAsync(indeg, 0, 2 * NN * sizeof(int), stream);
  deg_kernel<<<2048, 256, 0, stream>>>(src, dst, outdeg, indeg);
  norm_kernel<<<NBLK, 256, 0, stream>>>(outdeg, ns);
  scan1_kernel<<<NBLK, 256, 0, stream>>>(indeg, rowoff, bsum);
  scan2_kernel<<<1, 256, 0, stream>>>(bsum);
  scan3_kernel<<<NBLK, 256, 0, stream>>>(rowoff, bsum, cursor);
  bin_kernel<<<2048, 256, 0, stream>>>(src, dst, cursor, csr_src);

  // weight split (all 8 matrices)
  split_w_kernel<<<512, 256, 0, stream>>>(W_gc1, W_gc2, W_src, W_dst, Wblk);

  const int split_grid = RTILES * 16 * 16 / 256;

  // GC1: split(feature*ns) -> gemm (bf16 m) -> agg (split scaled by ns for GC2)
  split_h_kernel<<<split_grid, 256, 0, stream>>>(feature, ns, Ah, Al);
  gemm_mfma<<<GEMM_GRID, 256, 0, stream>>>(Ah, Al, Wblk + 0 * 32768, nullptr, mb);
  gc_agg_kernel<<<NN, 64, 0, stream>>>(mb, rowoff, indeg, csr_src,
                                       (const float2*)b_gc1, ns, Ah, Al);
  // GC2: gemm -> agg (split unscaled; doubles as GAT1's residual)
  gemm_mfma<<<GEMM_GRID, 256, 0, stream>>>(Ah, Al, Wblk + 1 * 32768, nullptr, mb);
  gc_agg_kernel<<<NN, 64, 0, stream>>>(mb, rowoff, indeg, csr_src,
                                       (const float2*)b_gc2, nullptr, Ah, Al);

  // GATv2 x3: fused fs/fd GEMM, h carried in the split; last layer emits fp32 h0
  for (int i = 0; i < 3; ++i) {
    gemm_dual<<<2 * GEMM_GRID, 256, 0, stream>>>(Ah, Al,
        Wblk + (2 + i) * 32768, Wblk + (5 + i) * 32768,
        b_src + i * HIDD, b_dst + i * HIDD, fsb, fdb);
    bool last = (i == 2);
    gat_node_kernel<<<NN, 64, 0, stream>>>(fsb, fdb,
                                           attn + i * HEADS * DHH,
                                           rowoff, indeg, csr_src, Ah, Al,
                                           last ? (float2*)h0 : nullptr);
  }

  // pooling + MLP
  hipMemsetAsync(hg, 0, GG * HIDD * sizeof(float), stream);
  pool_kernel<<<GG * 8, 128, 0, stream>>>(h0, n2g, (unsigned*)hg);
  mlp_kernel<<<GG, 128, 0, stream>>>(hg, Wc1, bc1, Wc2, bc2, Wc3, bc3, (float*)d_out);
}

// Round 10
// 612.723 us; speedup vs baseline: 1.1602x; 1.1602x over previous
//
#include <hip/hip_runtime.h>
#include <hip/hip_bf16.h>

#define NN 50000
#define EE 500000
#define GG 64
#define HIDD 128
#define HEADS 8
#define DHH 16
#define NBLK ((NN + 255) / 256)   // 196
#define RTILES 3128               // ceil(50000/16) rowtiles of 16
#define GEMM_GRID 391             // ceil(50000/128)

typedef __bf16 bf16x8 __attribute__((ext_vector_type(8)));
typedef float f32x4 __attribute__((ext_vector_type(4)));

// 8-lane sum reduce, pure DPP: quad xor1, quad xor2, cross-quad (row_half_mirror).
__device__ inline float rowsum8(float y) {
  int t;
  t = __builtin_amdgcn_mov_dpp(__float_as_int(y), 0xB1, 0xF, 0xF, true);  y += __int_as_float(t);
  t = __builtin_amdgcn_mov_dpp(__float_as_int(y), 0x4E, 0xF, 0xF, true);  y += __int_as_float(t);
  t = __builtin_amdgcn_mov_dpp(__float_as_int(y), 0x141, 0xF, 0xF, true); y += __int_as_float(t);
  return y;
}

__device__ inline float2 unpk2(unsigned u) {
  return make_float2(__uint_as_float(u << 16), __uint_as_float(u & 0xFFFF0000u));
}

// blocked bf16 fragment offset for element (row, 8-col-group kc)
__device__ inline int frag_off(int row, int kc) {
  return (row >> 4) * 2048 + (kc >> 2) * 512 + ((row & 15) + (kc & 3) * 16) * 8;
}

// ---------------- degree ----------------
__global__ void deg_kernel(const int* __restrict__ src, const int* __restrict__ dst,
                           int* __restrict__ outdeg, int* __restrict__ indeg) {
  int i = blockIdx.x * blockDim.x + threadIdx.x;
  int stride = gridDim.x * blockDim.x;
  for (; i < EE; i += stride) {
    atomicAdd(&outdeg[src[i]], 1);
    atomicAdd(&indeg[dst[i]], 1);
  }
}

__global__ void norm_kernel(const int* __restrict__ outdeg, float* __restrict__ ns) {
  int i = blockIdx.x * blockDim.x + threadIdx.x;
  if (i < NN) ns[i] = rsqrtf((float)max(outdeg[i], 1));
}

// ---------------- hierarchical exclusive scan ----------------
__global__ __launch_bounds__(256) void scan1_kernel(const int* __restrict__ deg,
                                                    int* __restrict__ excl,
                                                    int* __restrict__ bsum) {
  __shared__ int buf[256];
  int t = threadIdx.x;
  int idx = blockIdx.x * 256 + t;
  int v = (idx < NN) ? deg[idx] : 0;
  buf[t] = v;
  __syncthreads();
#pragma unroll
  for (int off = 1; off < 256; off <<= 1) {
    int tmp = (t >= off) ? buf[t - off] : 0;
    __syncthreads();
    buf[t] += tmp;
    __syncthreads();
  }
  if (idx < NN) excl[idx] = buf[t] - v;
  if (t == 255) bsum[blockIdx.x] = buf[255];
}

__global__ __launch_bounds__(256) void scan2_kernel(int* __restrict__ bsum) {
  __shared__ int buf[256];
  int t = threadIdx.x;
  int v = (t < NBLK) ? bsum[t] : 0;
  buf[t] = v;
  __syncthreads();
#pragma unroll
  for (int off = 1; off < 256; off <<= 1) {
    int tmp = (t >= off) ? buf[t - off] : 0;
    __syncthreads();
    buf[t] += tmp;
    __syncthreads();
  }
  if (t < NBLK) bsum[t] = buf[t] - v;
}

__global__ __launch_bounds__(256) void scan3_kernel(int* __restrict__ excl,
                                                    const int* __restrict__ bsum,
                                                    int* __restrict__ cursor) {
  int idx = blockIdx.x * 256 + threadIdx.x;
  if (idx < NN) {
    int v = excl[idx] + bsum[blockIdx.x];
    excl[idx] = v;
    cursor[idx] = v;
  }
}

__global__ void bin_kernel(const int* __restrict__ src, const int* __restrict__ dst,
                           int* __restrict__ cursor, int* __restrict__ csr_src) {
  int i = blockIdx.x * blockDim.x + threadIdx.x;
  int stride = gridDim.x * blockDim.x;
  for (; i < EE; i += stride) {
    int pos = atomicAdd(&cursor[dst[i]], 1);
    csr_src[pos] = src[i];
  }
}

// ---------------- bf16 hi/lo weight split (transposed, k-blocked, pre-swizzled) ----------------
__global__ __launch_bounds__(256) void split_w_kernel(
    const float* __restrict__ W_gc1, const float* __restrict__ W_gc2,
    const float* __restrict__ W_src, const float* __restrict__ W_dst,
    __bf16* __restrict__ Wblk)
{
  int tid = blockIdx.x * 256 + threadIdx.x;   // 8 * 16384
  int m = tid >> 14;
  int kn = tid & 16383;
  int k = kn >> 7, n = kn & 127;
  const float* Wm = (m == 0) ? W_gc1 : (m == 1) ? W_gc2
                   : (m < 5) ? (W_src + (m - 2) * 16384) : (W_dst + (m - 5) * 16384);
  float v = Wm[kn];
  __bf16 h = (__bf16)v;
  __bf16 l = (__bf16)(v - (float)h);
  int ks = k >> 5;
  int L = n * 32 + ((k >> 3) & 3) * 8 + (k & 7);
  int swz = L ^ ((n & 7) << 3);
  __bf16* dstp = Wblk + m * 32768 + ks * 8192;
  dstp[swz] = h;
  dstp[4096 + swz] = l;
}

// ---------------- bf16 hi/lo input split (feature only) ----------------
__global__ __launch_bounds__(256) void split_h_kernel(
    const float* __restrict__ X, const float* __restrict__ scale,
    __bf16* __restrict__ Ah, __bf16* __restrict__ Al)
{
  int tid = blockIdx.x * 256 + threadIdx.x;   // RTILES*16*16
  int row = tid >> 4, kc = tid & 15;
  float v[8];
  if (row < NN) {
    const float4* p = (const float4*)(X + row * 128 + kc * 8);
    float4 a = p[0], b = p[1];
    float s = scale ? scale[row] : 1.f;
    v[0] = a.x * s; v[1] = a.y * s; v[2] = a.z * s; v[3] = a.w * s;
    v[4] = b.x * s; v[5] = b.y * s; v[6] = b.z * s; v[7] = b.w * s;
  } else {
#pragma unroll
    for (int i = 0; i < 8; ++i) v[i] = 0.f;
  }
  bf16x8 hi, lo;
#pragma unroll
  for (int i = 0; i < 8; ++i) {
    __bf16 h = (__bf16)v[i];
    hi[i] = h;
    lo[i] = (__bf16)(v[i] - (float)h);
  }
  int off = frag_off(row, kc);
  *(bf16x8*)(Ah + off) = hi;
  *(bf16x8*)(Al + off) = lo;
}

// ---------------- bf16x3 MFMA GEMM core ----------------
__device__ inline void gemm_body(
    const __bf16* __restrict__ Ah, const __bf16* __restrict__ Al,
    const __bf16* __restrict__ Wmat, const float* __restrict__ bias,
    __bf16* __restrict__ outb, int bx, __bf16* wt)
{
  int tid = threadIdx.x;
  int wid = tid >> 6, lane = tid & 63;
  int wr = wid >> 1, wc = wid & 1;
  int l15 = lane & 15, l4 = lane >> 4;
  f32x4 acc[4][4];
#pragma unroll
  for (int a = 0; a < 4; ++a)
#pragma unroll
    for (int b = 0; b < 4; ++b) acc[a][b] = (f32x4){0.f, 0.f, 0.f, 0.f};
  int rowtile0 = bx * 8 + wr * 4;

  for (int ks = 0; ks < 4; ++ks) {
    {
      const bf16x8* g = (const bf16x8*)(Wmat + ks * 8192);
      bf16x8* l = (bf16x8*)wt;
      l[tid]       = g[tid];
      l[tid + 256] = g[tid + 256];
      l[tid + 512] = g[tid + 512];
      l[tid + 768] = g[tid + 768];
    }
    bf16x8 ah[4], al[4];
#pragma unroll
    for (int rt = 0; rt < 4; ++rt) {
      int off = (rowtile0 + rt) * 2048 + ks * 512 + lane * 8;
      ah[rt] = *(const bf16x8*)(Ah + off);
      al[rt] = *(const bf16x8*)(Al + off);
    }
    __syncthreads();
#pragma unroll
    for (int ct = 0; ct < 4; ++ct) {
      int n = wc * 64 + ct * 16 + l15;
      int ei = (n * 32 + l4 * 8) ^ ((n & 7) << 3);
      bf16x8 bh = *(const bf16x8*)(wt + ei);
      bf16x8 bl = *(const bf16x8*)(wt + 4096 + ei);
#pragma unroll
      for (int rt = 0; rt < 4; ++rt) {
        acc[rt][ct] = __builtin_amdgcn_mfma_f32_16x16x32_bf16(ah[rt], bh, acc[rt][ct], 0, 0, 0);
        acc[rt][ct] = __builtin_amdgcn_mfma_f32_16x16x32_bf16(ah[rt], bl, acc[rt][ct], 0, 0, 0);
        acc[rt][ct] = __builtin_amdgcn_mfma_f32_16x16x32_bf16(al[rt], bh, acc[rt][ct], 0, 0, 0);
      }
    }
    __syncthreads();
  }
  int rowbase = bx * 128 + wr * 64;
#pragma unroll
  for (int ct = 0; ct < 4; ++ct) {
    int col = wc * 64 + ct * 16 + l15;
    float b = bias ? bias[col] : 0.f;
#pragma unroll
    for (int rt = 0; rt < 4; ++rt) {
#pragma unroll
      for (int r = 0; r < 4; ++r) {
        int row = rowbase + rt * 16 + l4 * 4 + r;
        if (row < NN) outb[row * 128 + col] = (__bf16)(acc[rt][ct][r] + b);
      }
    }
  }
}

__global__ __launch_bounds__(256) void gemm_mfma(
    const __bf16* __restrict__ Ah, const __bf16* __restrict__ Al,
    const __bf16* __restrict__ Wmat, const float* __restrict__ bias,
    __bf16* __restrict__ outb)
{
  __shared__ __bf16 wt[8192];
  gemm_body(Ah, Al, Wmat, bias, outb, blockIdx.x, wt);
}

// fs and fd GEMMs of one GAT layer in a single dispatch (grid = 2*GEMM_GRID)
__global__ __launch_bounds__(256) void gemm_dual(
    const __bf16* __restrict__ Ah, const __bf16* __restrict__ Al,
    const __bf16* __restrict__ W0, const __bf16* __restrict__ W1,
    const float* __restrict__ bias0, const float* __restrict__ bias1,
    __bf16* __restrict__ out0, __bf16* __restrict__ out1)
{
  __shared__ __bf16 wt[8192];
  int which = (blockIdx.x >= GEMM_GRID);
  int bx = blockIdx.x - (which ? GEMM_GRID : 0);
  gemm_body(Ah, Al, which ? W1 : W0, which ? bias1 : bias0,
            which ? out1 : out0, bx, wt);
}

// ---------------- GraphConv aggregation: bf16 gather, 64 thr/node, x4 unroll ----------------
__global__ __launch_bounds__(64) void gc_agg_kernel(
    const __bf16* __restrict__ mb, const int* __restrict__ rowoff,
    const int* __restrict__ indeg, const int* __restrict__ csr_src,
    const float2* __restrict__ bias2, const float* __restrict__ nsrow,
    float2* __restrict__ out2,        // null = skip fp32 write
    __bf16* __restrict__ Ah, __bf16* __restrict__ Al)   // null = skip split
{
  __shared__ float buf[128];
  int d = blockIdx.x, c = threadIdx.x;
  int ro = rowoff[d], dg = indeg[d];
  float2 a0 = {0.f, 0.f}, a1 = {0.f, 0.f}, a2 = {0.f, 0.f}, a3 = {0.f, 0.f};
  int j = 0;
  for (; j + 4 <= dg; j += 4) {
    int s0 = csr_src[ro + j], s1 = csr_src[ro + j + 1];
    int s2 = csr_src[ro + j + 2], s3 = csr_src[ro + j + 3];
    float2 v0 = unpk2(*(const unsigned*)(mb + s0 * 128 + 2 * c));
    float2 v1 = unpk2(*(const unsigned*)(mb + s1 * 128 + 2 * c));
    float2 v2 = unpk2(*(const unsigned*)(mb + s2 * 128 + 2 * c));
    float2 v3 = unpk2(*(const unsigned*)(mb + s3 * 128 + 2 * c));
    a0.x += v0.x; a0.y += v0.y; a1.x += v1.x; a1.y += v1.y;
    a2.x += v2.x; a2.y += v2.y; a3.x += v3.x; a3.y += v3.y;
  }
  for (; j < dg; ++j) {
    float2 v = unpk2(*(const unsigned*)(mb + csr_src[ro + j] * 128 + 2 * c));
    a0.x += v.x; a0.y += v.y;
  }
  float accx = (a0.x + a1.x) + (a2.x + a3.x);
  float accy = (a0.y + a1.y) + (a2.y + a3.y);
  float ndv = rsqrtf((float)max(dg, 1));
  float2 b = bias2[c];
  float vx = fmaxf(accx * ndv + b.x, 0.f);
  float vy = fmaxf(accy * ndv + b.y, 0.f);
  if (out2) out2[d * 64 + c] = make_float2(vx, vy);
  if (Ah) {
    float s = nsrow ? nsrow[d] : 1.f;
    ((float2*)buf)[c] = make_float2(vx * s, vy * s);
    __syncthreads();
    if (c < 32) {
      int kc = c & 15;
      int off = frag_off(d, kc);
      bf16x8 pk;
      if (c < 16) {
#pragma unroll
        for (int i = 0; i < 8; ++i) pk[i] = (__bf16)buf[kc * 8 + i];
        *(bf16x8*)(Ah + off) = pk;
      } else {
#pragma unroll
        for (int i = 0; i < 8; ++i) {
          float x = buf[kc * 8 + i];
          __bf16 hh = (__bf16)x;
          pk[i] = (__bf16)(x - (float)hh);
        }
        *(bf16x8*)(Al + off) = pk;
      }
    }
  }
}

// ---------------- Fused GATv2: bf16 fs gather + bf16 fd, DPP reduce, online softmax ----------------
__global__ __launch_bounds__(64) void gat_node_kernel(
    const __bf16* __restrict__ fsb,   // [N][128] bf16
    const __bf16* __restrict__ fdb,   // [N][128] bf16
    const float* __restrict__ attn,
    const int* __restrict__ rowoff, const int* __restrict__ indeg,
    const int* __restrict__ csr_src,
    float2* __restrict__ h2,          // in/out fp32
    __bf16* __restrict__ Ah, __bf16* __restrict__ Al)   // null = skip split
{
  __shared__ float buf[128];
  int d = blockIdx.x, c = threadIdx.x;
  int ro = rowoff[d], dg = indeg[d];
  float2 fdp = unpk2(*(const unsigned*)(fdb + d * 128 + 2 * c));
  float2 ap = ((const float2*)attn)[c];
  float mA = -INFINITY, sA = 0.f; float2 aA = {0.f, 0.f};
  float mB = -INFINITY, sB = 0.f; float2 aB = {0.f, 0.f};
  int j = 0;
  for (; j + 2 <= dg; j += 2) {
    int s0 = csr_src[ro + j], s1 = csr_src[ro + j + 1];
    float2 f0 = unpk2(*(const unsigned*)(fsb + s0 * 128 + 2 * c));
    float2 f1 = unpk2(*(const unsigned*)(fsb + s1 * 128 + 2 * c));
    float x0 = f0.x + fdp.x; x0 = fmaxf(x0, 0.f) + 0.2f * fminf(x0, 0.f);
    float z0 = f0.y + fdp.y; z0 = fmaxf(z0, 0.f) + 0.2f * fminf(z0, 0.f);
    float x1 = f1.x + fdp.x; x1 = fmaxf(x1, 0.f) + 0.2f * fminf(x1, 0.f);
    float z1 = f1.y + fdp.y; z1 = fmaxf(z1, 0.f) + 0.2f * fminf(z1, 0.f);
    float y0 = rowsum8(ap.x * x0 + ap.y * z0);
    float y1 = rowsum8(ap.x * x1 + ap.y * z1);
    float nm = fmaxf(mA, y0);
    float sc = __expf(mA - nm), p = __expf(y0 - nm);
    sA = sA * sc + p; aA.x = aA.x * sc + p * f0.x; aA.y = aA.y * sc + p * f0.y; mA = nm;
    nm = fmaxf(mB, y1);
    sc = __expf(mB - nm); p = __expf(y1 - nm);
    sB = sB * sc + p; aB.x = aB.x * sc + p * f1.x; aB.y = aB.y * sc + p * f1.y; mB = nm;
  }
  if (j < dg) {
    int s0 = csr_src[ro + j];
    float2 f0 = unpk2(*(const unsigned*)(fsb + s0 * 128 + 2 * c));
    float x0 = f0.x + fdp.x; x0 = fmaxf(x0, 0.f) + 0.2f * fminf(x0, 0.f);
    float z0 = f0.y + fdp.y; z0 = fmaxf(z0, 0.f) + 0.2f * fminf(z0, 0.f);
    float y0 = rowsum8(ap.x * x0 + ap.y * z0);
    float nm = fmaxf(mA, y0);
    float sc = __expf(mA - nm), p = __expf(y0 - nm);
    sA = sA * sc + p; aA.x = aA.x * sc + p * f0.x; aA.y = aA.y * sc + p * f0.y; mA = nm;
  }
  float ox = 0.f, oy = 0.f;
  if (dg > 0) {
    float M = fmaxf(mA, mB);
    float eA = __expf(mA - M), eB = __expf(mB - M);   // exp(-inf)=0 handles dg==1
    float inv = 1.f / (sA * eA + sB * eB);
    ox = (aA.x * eA + aB.x * eB) * inv;
    oy = (aA.y * eA + aB.y * eB) * inv;
  }
  float2 hv = h2[d * 64 + c];
  float vx = fmaxf(ox + hv.x, 0.f);
  float vy = fmaxf(oy + hv.y, 0.f);
  h2[d * 64 + c] = make_float2(vx, vy);
  if (Ah) {
    ((float2*)buf)[c] = make_float2(vx, vy);
    __syncthreads();
    if (c < 32) {
      int kc = c & 15;
      int off = frag_off(d, kc);
      bf16x8 pk;
      if (c < 16) {
#pragma unroll
        for (int i = 0; i < 8; ++i) pk[i] = (__bf16)buf[kc * 8 + i];
        *(bf16x8*)(Ah + off) = pk;
      } else {
#pragma unroll
        for (int i = 0; i < 8; ++i) {
          float x = buf[kc * 8 + i];
          __bf16 hh = (__bf16)x;
          pk[i] = (__bf16)(x - (float)hh);
        }
        *(bf16x8*)(Al + off) = pk;
      }
    }
  }
}

// ---------------- pooling (n2g sorted: per-graph range + few atomics) ----------------
__global__ __launch_bounds__(128) void pool_kernel(const float* __restrict__ h,
                                                   const int* __restrict__ n2g,
                                                   unsigned* __restrict__ hg)
{
  int g = blockIdx.x >> 3, chunk = blockIdx.x & 7, c = threadIdx.x;
  int lo = 0, hi = NN;
  while (lo < hi) { int mid = (lo + hi) >> 1; if (n2g[mid] < g) lo = mid + 1; else hi = mid; }
  int start = lo;
  hi = NN;
  while (lo < hi) { int mid = (lo + hi) >> 1; if (n2g[mid] < g + 1) lo = mid + 1; else hi = mid; }
  int end = lo;
  int len = end - start;
  int s = start + (int)(((long long)len * chunk) >> 3);
  int e = start + (int)(((long long)len * (chunk + 1)) >> 3);
  float m = 0.f;
  for (int r = s; r < e; ++r) m = fmaxf(m, h[r * 128 + c]);
  atomicMax(&hg[g * 128 + c], __float_as_uint(m));
}

__global__ __launch_bounds__(128) void mlp_kernel(
    const float* __restrict__ hg,
    const float* __restrict__ Wc1, const float* __restrict__ bc1,
    const float* __restrict__ Wc2, const float* __restrict__ bc2,
    const float* __restrict__ Wc3, const float* __restrict__ bc3,
    float* __restrict__ out)
{
  __shared__ float x[128], z1[128], z2[64];
  int g = blockIdx.x, t = threadIdx.x;
  x[t] = hg[g * 128 + t];
  __syncthreads();
  float acc = bc1[t];
  for (int k = 0; k < 128; ++k) acc += x[k] * Wc1[k * 128 + t];
  z1[t] = fmaxf(acc, 0.f);
  __syncthreads();
  if (t < 64) {
    float a2 = bc2[t];
    for (int k = 0; k < 128; ++k) a2 += z1[k] * Wc2[k * 64 + t];
    z2[t] = fmaxf(a2, 0.f);
  }
  __syncthreads();
#pragma unroll
  for (int p = 0; p < 2; ++p) {
    int c = t + p * 128;
    float a3 = bc3[c];
    for (int k = 0; k < 64; ++k) a3 += z2[k] * Wc3[k * 256 + c];
    out[g * 256 + c] = a3;
  }
}

// ---------------- launch ----------------
extern "C" void kernel_launch(void* const* d_in, const int* in_sizes, int n_in,
                              void* d_out, int out_size, void* d_ws, size_t ws_size,
                              hipStream_t stream)
{
  const float* feature = (const float*)d_in[0];
  const float* W_gc1 = (const float*)d_in[1];
  const float* b_gc1 = (const float*)d_in[2];
  const float* W_gc2 = (const float*)d_in[3];
  const float* b_gc2 = (const float*)d_in[4];
  const float* W_src = (const float*)d_in[5];
  const float* b_src = (const float*)d_in[6];
  const float* W_dst = (const float*)d_in[7];
  const float* b_dst = (const float*)d_in[8];
  const float* attn  = (const float*)d_in[9];
  const float* Wc1 = (const float*)d_in[10];
  const float* bc1 = (const float*)d_in[11];
  const float* Wc2 = (const float*)d_in[12];
  const float* bc2 = (const float*)d_in[13];
  const float* Wc3 = (const float*)d_in[14];
  const float* bc3 = (const float*)d_in[15];
  const int* src = (const int*)d_in[16];
  const int* dst = (const int*)d_in[17];
  const int* n2g = (const int*)d_in[18];

  char* base = (char*)d_ws;
  int* indeg  = (int*)base;            base += NN * sizeof(int);
  int* outdeg = (int*)base;            base += NN * sizeof(int);
  int* rowoff = (int*)base;            base += NN * sizeof(int);
  int* cursor = (int*)base;            base += NN * sizeof(int);
  int* bsum   = (int*)base;            base += 256 * sizeof(int);
  int* csr_src = (int*)base;           base += EE * sizeof(int);
  float* ns = (float*)base;            base += NN * sizeof(float);
  float* h0 = (float*)base;            base += (size_t)NN * HIDD * sizeof(float);
  __bf16* fsb = (__bf16*)base;         base += (size_t)NN * HIDD * sizeof(__bf16);
  __bf16* fdb = (__bf16*)base;         base += (size_t)NN * HIDD * sizeof(__bf16);
  __bf16* mb  = (__bf16*)base;         base += (size_t)NN * HIDD * sizeof(__bf16);
  __bf16* Ah = (__bf16*)base;          base += (size_t)RTILES * 2048 * sizeof(__bf16);
  __bf16* Al = (__bf16*)base;          base += (size_t)RTILES * 2048 * sizeof(__bf16);
  __bf16* Wblk = (__bf16*)base;        base += (size_t)8 * 32768 * sizeof(__bf16);
  float* hg = (float*)base;            base += GG * HIDD * sizeof(float);

  // degrees, norms, CSR
  hipMemsetAsync(indeg, 0, 2 * NN * sizeof(int), stream);
  deg_kernel<<<2048, 256, 0, stream>>>(src, dst, outdeg, indeg);
  norm_kernel<<<NBLK, 256, 0, stream>>>(outdeg, ns);
  scan1_kernel<<<NBLK, 256, 0, stream>>>(indeg, rowoff, bsum);
  scan2_kernel<<<1, 256, 0, stream>>>(bsum);
  scan3_kernel<<<NBLK, 256, 0, stream>>>(rowoff, bsum, cursor);
  bin_kernel<<<2048, 256, 0, stream>>>(src, dst, cursor, csr_src);

  // weight split (all 8 matrices)
  split_w_kernel<<<512, 256, 0, stream>>>(W_gc1, W_gc2, W_src, W_dst, Wblk);

  const int split_grid = RTILES * 16 * 16 / 256;

  // GC1: split(feature*ns) -> gemm (bf16 m) -> agg (writes next split, scaled by ns)
  split_h_kernel<<<split_grid, 256, 0, stream>>>(feature, ns, Ah, Al);
  gemm_mfma<<<GEMM_GRID, 256, 0, stream>>>(Ah, Al, Wblk + 0 * 32768, nullptr, mb);
  gc_agg_kernel<<<NN, 64, 0, stream>>>(mb, rowoff, indeg, csr_src,
                                       (const float2*)b_gc1, ns, nullptr, Ah, Al);
  // GC2: gemm (bf16 m) -> agg (writes h0 + unscaled split for GAT1)
  gemm_mfma<<<GEMM_GRID, 256, 0, stream>>>(Ah, Al, Wblk + 1 * 32768, nullptr, mb);
  gc_agg_kernel<<<NN, 64, 0, stream>>>(mb, rowoff, indeg, csr_src,
                                       (const float2*)b_gc2, nullptr, (float2*)h0, Ah, Al);

  // GATv2 x3: fused fs/fd GEMM (one dispatch), h0 fp32 carried, split for next layer
  for (int i = 0; i < 3; ++i) {
    gemm_dual<<<2 * GEMM_GRID, 256, 0, stream>>>(Ah, Al,
        Wblk + (2 + i) * 32768, Wblk + (5 + i) * 32768,
        b_src + i * HIDD, b_dst + i * HIDD, fsb, fdb);
    bool last = (i == 2);
    gat_node_kernel<<<NN, 64, 0, stream>>>(fsb, fdb,
                                           attn + i * HEADS * DHH,
                                           rowoff, indeg, csr_src, (float2*)h0,
                                           last ? nullptr : Ah, last ? nullptr : Al);
  }

  // pooling + MLP
  hipMemsetAsync(hg, 0, GG * HIDD * sizeof(float), stream);
  pool_kernel<<<GG * 8, 128, 0, stream>>>(h0, n2g, (unsigned*)hg);
  mlp_kernel<<<GG, 128, 0, stream>>>(hg, Wc1, bc1, Wc2, bc2, Wc3, bc3, (float*)d_out);
}

// Round 11
// 487.285 us; speedup vs baseline: 1.4588x; 1.2574x over previous
//
#include <hip/hip_runtime.h>
#include <hip/hip_bf16.h>

#define NN 50000
#define EE 500000
#define GG 64
#define HIDD 128
#define HEADS 8
#define DHH 16
#define NBLK ((NN + 255) / 256)   // 196
#define RTILES 3128               // ceil(50000/16) rowtiles of 16
#define GEMM_GRID 782             // RTILES/4 row-blocks of 64 rows

typedef __bf16 bf16x8 __attribute__((ext_vector_type(8)));
typedef float f32x4 __attribute__((ext_vector_type(4)));

// 8-lane sum reduce, pure DPP: quad xor1, quad xor2, cross-quad (row_half_mirror).
__device__ inline float rowsum8(float y) {
  int t;
  t = __builtin_amdgcn_mov_dpp(__float_as_int(y), 0xB1, 0xF, 0xF, true);  y += __int_as_float(t);
  t = __builtin_amdgcn_mov_dpp(__float_as_int(y), 0x4E, 0xF, 0xF, true);  y += __int_as_float(t);
  t = __builtin_amdgcn_mov_dpp(__float_as_int(y), 0x141, 0xF, 0xF, true); y += __int_as_float(t);
  return y;
}

__device__ inline float2 unpk2(unsigned u) {
  return make_float2(__uint_as_float(u << 16), __uint_as_float(u & 0xFFFF0000u));
}

// blocked bf16 fragment offset for element (row, 8-col-group kc)
__device__ inline int frag_off(int row, int kc) {
  return (row >> 4) * 2048 + (kc >> 2) * 512 + ((row & 15) + (kc & 3) * 16) * 8;
}

// ---------------- degree ----------------
__global__ void deg_kernel(const int* __restrict__ src, const int* __restrict__ dst,
                           int* __restrict__ outdeg, int* __restrict__ indeg) {
  int i = blockIdx.x * blockDim.x + threadIdx.x;
  int stride = gridDim.x * blockDim.x;
  for (; i < EE; i += stride) {
    atomicAdd(&outdeg[src[i]], 1);
    atomicAdd(&indeg[dst[i]], 1);
  }
}

__global__ void norm_kernel(const int* __restrict__ outdeg, float* __restrict__ ns) {
  int i = blockIdx.x * blockDim.x + threadIdx.x;
  if (i < NN) ns[i] = rsqrtf((float)max(outdeg[i], 1));
}

// ---------------- hierarchical exclusive scan ----------------
__global__ __launch_bounds__(256) void scan1_kernel(const int* __restrict__ deg,
                                                    int* __restrict__ excl,
                                                    int* __restrict__ bsum) {
  __shared__ int buf[256];
  int t = threadIdx.x;
  int idx = blockIdx.x * 256 + t;
  int v = (idx < NN) ? deg[idx] : 0;
  buf[t] = v;
  __syncthreads();
#pragma unroll
  for (int off = 1; off < 256; off <<= 1) {
    int tmp = (t >= off) ? buf[t - off] : 0;
    __syncthreads();
    buf[t] += tmp;
    __syncthreads();
  }
  if (idx < NN) excl[idx] = buf[t] - v;
  if (t == 255) bsum[blockIdx.x] = buf[255];
}

__global__ __launch_bounds__(256) void scan2_kernel(int* __restrict__ bsum) {
  __shared__ int buf[256];
  int t = threadIdx.x;
  int v = (t < NBLK) ? bsum[t] : 0;
  buf[t] = v;
  __syncthreads();
#pragma unroll
  for (int off = 1; off < 256; off <<= 1) {
    int tmp = (t >= off) ? buf[t - off] : 0;
    __syncthreads();
    buf[t] += tmp;
    __syncthreads();
  }
  if (t < NBLK) bsum[t] = buf[t] - v;
}

__global__ __launch_bounds__(256) void scan3_kernel(int* __restrict__ excl,
                                                    const int* __restrict__ bsum,
                                                    int* __restrict__ cursor) {
  int idx = blockIdx.x * 256 + threadIdx.x;
  if (idx < NN) {
    int v = excl[idx] + bsum[blockIdx.x];
    excl[idx] = v;
    cursor[idx] = v;
  }
}

__global__ void bin_kernel(const int* __restrict__ src, const int* __restrict__ dst,
                           int* __restrict__ cursor, int* __restrict__ csr_src) {
  int i = blockIdx.x * blockDim.x + threadIdx.x;
  int stride = gridDim.x * blockDim.x;
  for (; i < EE; i += stride) {
    int pos = atomicAdd(&cursor[dst[i]], 1);
    csr_src[pos] = src[i];
  }
}

// ---------------- bf16 hi/lo weight split (transposed, k-blocked, pre-swizzled) ----------------
__global__ __launch_bounds__(256) void split_w_kernel(
    const float* __restrict__ W_gc1, const float* __restrict__ W_gc2,
    const float* __restrict__ W_src, const float* __restrict__ W_dst,
    __bf16* __restrict__ Wblk)
{
  int tid = blockIdx.x * 256 + threadIdx.x;   // 8 * 16384
  int m = tid >> 14;
  int kn = tid & 16383;
  int k = kn >> 7, n = kn & 127;
  const float* Wm = (m == 0) ? W_gc1 : (m == 1) ? W_gc2
                   : (m < 5) ? (W_src + (m - 2) * 16384) : (W_dst + (m - 5) * 16384);
  float v = Wm[kn];
  __bf16 h = (__bf16)v;
  __bf16 l = (__bf16)(v - (float)h);
  int ks = k >> 5;
  int L = n * 32 + ((k >> 3) & 3) * 8 + (k & 7);
  int swz = L ^ ((n & 7) << 3);
  __bf16* dstp = Wblk + m * 32768 + ks * 8192;
  dstp[swz] = h;
  dstp[4096 + swz] = l;
}

// ---------------- bf16 hi/lo input split (feature only) ----------------
__global__ __launch_bounds__(256) void split_h_kernel(
    const float* __restrict__ X, const float* __restrict__ scale,
    __bf16* __restrict__ Ah, __bf16* __restrict__ Al)
{
  int tid = blockIdx.x * 256 + threadIdx.x;   // RTILES*16*16
  int row = tid >> 4, kc = tid & 15;
  float v[8];
  if (row < NN) {
    const float4* p = (const float4*)(X + row * 128 + kc * 8);
    float4 a = p[0], b = p[1];
    float s = scale ? scale[row] : 1.f;
    v[0] = a.x * s; v[1] = a.y * s; v[2] = a.z * s; v[3] = a.w * s;
    v[4] = b.x * s; v[5] = b.y * s; v[6] = b.z * s; v[7] = b.w * s;
  } else {
#pragma unroll
    for (int i = 0; i < 8; ++i) v[i] = 0.f;
  }
  bf16x8 hi, lo;
#pragma unroll
  for (int i = 0; i < 8; ++i) {
    __bf16 h = (__bf16)v[i];
    hi[i] = h;
    lo[i] = (__bf16)(v[i] - (float)h);
  }
  int off = frag_off(row, kc);
  *(bf16x8*)(Ah + off) = hi;
  *(bf16x8*)(Al + off) = lo;
}

// ---------------- bf16x3 MFMA GEMM: 64-row blocks, wave = 32r x 64c ----------------
// acc[2][4] = 32 VGPR (vs 64 in the 128-row version) -> ~100 VGPR total,
// ~5 waves/SIMD occupancy to hide global A-load latency. W duplicated reads
// are L2-resident (64KB/matrix). MFMA order per tile unchanged (bit-identical).
__global__ __launch_bounds__(256) void gemm_mfma(
    const __bf16* __restrict__ Ah, const __bf16* __restrict__ Al,
    const __bf16* __restrict__ Wmat, const float* __restrict__ bias,
    __bf16* __restrict__ outb)
{
  __shared__ __bf16 wt[8192];
  int tid = threadIdx.x;
  int wid = tid >> 6, lane = tid & 63;
  int wr = wid >> 1, wc = wid & 1;       // wr: 32-row half, wc: 64-col half
  int l15 = lane & 15, l4 = lane >> 4;
  f32x4 acc[2][4];
#pragma unroll
  for (int a = 0; a < 2; ++a)
#pragma unroll
    for (int b = 0; b < 4; ++b) acc[a][b] = (f32x4){0.f, 0.f, 0.f, 0.f};
  int rowtile0 = blockIdx.x * 4 + wr * 2;

  for (int ks = 0; ks < 4; ++ks) {
    {
      const bf16x8* g = (const bf16x8*)(Wmat + ks * 8192);
      bf16x8* l = (bf16x8*)wt;
      l[tid]       = g[tid];
      l[tid + 256] = g[tid + 256];
      l[tid + 512] = g[tid + 512];
      l[tid + 768] = g[tid + 768];
    }
    bf16x8 ah[2], al[2];
#pragma unroll
    for (int rt = 0; rt < 2; ++rt) {
      int off = (rowtile0 + rt) * 2048 + ks * 512 + lane * 8;
      ah[rt] = *(const bf16x8*)(Ah + off);
      al[rt] = *(const bf16x8*)(Al + off);
    }
    __syncthreads();
#pragma unroll
    for (int ct = 0; ct < 4; ++ct) {
      int n = wc * 64 + ct * 16 + l15;
      int ei = (n * 32 + l4 * 8) ^ ((n & 7) << 3);
      bf16x8 bh = *(const bf16x8*)(wt + ei);
      bf16x8 bl = *(const bf16x8*)(wt + 4096 + ei);
#pragma unroll
      for (int rt = 0; rt < 2; ++rt) {
        acc[rt][ct] = __builtin_amdgcn_mfma_f32_16x16x32_bf16(ah[rt], bh, acc[rt][ct], 0, 0, 0);
        acc[rt][ct] = __builtin_amdgcn_mfma_f32_16x16x32_bf16(ah[rt], bl, acc[rt][ct], 0, 0, 0);
        acc[rt][ct] = __builtin_amdgcn_mfma_f32_16x16x32_bf16(al[rt], bh, acc[rt][ct], 0, 0, 0);
      }
    }
    __syncthreads();
  }
  int rowbase = blockIdx.x * 64 + wr * 32;
#pragma unroll
  for (int ct = 0; ct < 4; ++ct) {
    int col = wc * 64 + ct * 16 + l15;
    float b = bias ? bias[col] : 0.f;
#pragma unroll
    for (int rt = 0; rt < 2; ++rt) {
#pragma unroll
      for (int r = 0; r < 4; ++r) {
        int row = rowbase + rt * 16 + l4 * 4 + r;
        if (row < NN) outb[row * 128 + col] = (__bf16)(acc[rt][ct][r] + b);
      }
    }
  }
}

// ---------------- GraphConv aggregation: bf16 gather, 64 thr/node, x4 unroll ----------------
__global__ __launch_bounds__(64) void gc_agg_kernel(
    const __bf16* __restrict__ mb, const int* __restrict__ rowoff,
    const int* __restrict__ indeg, const int* __restrict__ csr_src,
    const float2* __restrict__ bias2, const float* __restrict__ nsrow,
    float2* __restrict__ out2,        // null = skip fp32 write
    __bf16* __restrict__ Ah, __bf16* __restrict__ Al)   // null = skip split
{
  __shared__ float buf[128];
  int d = blockIdx.x, c = threadIdx.x;
  int ro = rowoff[d], dg = indeg[d];
  float2 a0 = {0.f, 0.f}, a1 = {0.f, 0.f}, a2 = {0.f, 0.f}, a3 = {0.f, 0.f};
  int j = 0;
  for (; j + 4 <= dg; j += 4) {
    int s0 = csr_src[ro + j], s1 = csr_src[ro + j + 1];
    int s2 = csr_src[ro + j + 2], s3 = csr_src[ro + j + 3];
    float2 v0 = unpk2(*(const unsigned*)(mb + s0 * 128 + 2 * c));
    float2 v1 = unpk2(*(const unsigned*)(mb + s1 * 128 + 2 * c));
    float2 v2 = unpk2(*(const unsigned*)(mb + s2 * 128 + 2 * c));
    float2 v3 = unpk2(*(const unsigned*)(mb + s3 * 128 + 2 * c));
    a0.x += v0.x; a0.y += v0.y; a1.x += v1.x; a1.y += v1.y;
    a2.x += v2.x; a2.y += v2.y; a3.x += v3.x; a3.y += v3.y;
  }
  for (; j < dg; ++j) {
    float2 v = unpk2(*(const unsigned*)(mb + csr_src[ro + j] * 128 + 2 * c));
    a0.x += v.x; a0.y += v.y;
  }
  float accx = (a0.x + a1.x) + (a2.x + a3.x);
  float accy = (a0.y + a1.y) + (a2.y + a3.y);
  float ndv = rsqrtf((float)max(dg, 1));
  float2 b = bias2[c];
  float vx = fmaxf(accx * ndv + b.x, 0.f);
  float vy = fmaxf(accy * ndv + b.y, 0.f);
  if (out2) out2[d * 64 + c] = make_float2(vx, vy);
  if (Ah) {
    float s = nsrow ? nsrow[d] : 1.f;
    ((float2*)buf)[c] = make_float2(vx * s, vy * s);
    __syncthreads();
    if (c < 32) {
      int kc = c & 15;
      int off = frag_off(d, kc);
      bf16x8 pk;
      if (c < 16) {
#pragma unroll
        for (int i = 0; i < 8; ++i) pk[i] = (__bf16)buf[kc * 8 + i];
        *(bf16x8*)(Ah + off) = pk;
      } else {
#pragma unroll
        for (int i = 0; i < 8; ++i) {
          float x = buf[kc * 8 + i];
          __bf16 hh = (__bf16)x;
          pk[i] = (__bf16)(x - (float)hh);
        }
        *(bf16x8*)(Al + off) = pk;
      }
    }
  }
}

// ---------------- Fused GATv2: bf16 fs gather + bf16 fd, DPP reduce, online softmax ----------------
__global__ __launch_bounds__(64) void gat_node_kernel(
    const __bf16* __restrict__ fsb,   // [N][128] bf16
    const __bf16* __restrict__ fdb,   // [N][128] bf16
    const float* __restrict__ attn,
    const int* __restrict__ rowoff, const int* __restrict__ indeg,
    const int* __restrict__ csr_src,
    float2* __restrict__ h2,          // in/out fp32
    __bf16* __restrict__ Ah, __bf16* __restrict__ Al)   // null = skip split
{
  __shared__ float buf[128];
  int d = blockIdx.x, c = threadIdx.x;
  int ro = rowoff[d], dg = indeg[d];
  float2 fdp = unpk2(*(const unsigned*)(fdb + d * 128 + 2 * c));
  float2 ap = ((const float2*)attn)[c];
  float mA = -INFINITY, sA = 0.f; float2 aA = {0.f, 0.f};
  float mB = -INFINITY, sB = 0.f; float2 aB = {0.f, 0.f};
  int j = 0;
  for (; j + 2 <= dg; j += 2) {
    int s0 = csr_src[ro + j], s1 = csr_src[ro + j + 1];
    float2 f0 = unpk2(*(const unsigned*)(fsb + s0 * 128 + 2 * c));
    float2 f1 = unpk2(*(const unsigned*)(fsb + s1 * 128 + 2 * c));
    float x0 = f0.x + fdp.x; x0 = fmaxf(x0, 0.f) + 0.2f * fminf(x0, 0.f);
    float z0 = f0.y + fdp.y; z0 = fmaxf(z0, 0.f) + 0.2f * fminf(z0, 0.f);
    float x1 = f1.x + fdp.x; x1 = fmaxf(x1, 0.f) + 0.2f * fminf(x1, 0.f);
    float z1 = f1.y + fdp.y; z1 = fmaxf(z1, 0.f) + 0.2f * fminf(z1, 0.f);
    float y0 = rowsum8(ap.x * x0 + ap.y * z0);
    float y1 = rowsum8(ap.x * x1 + ap.y * z1);
    float nm = fmaxf(mA, y0);
    float sc = __expf(mA - nm), p = __expf(y0 - nm);
    sA = sA * sc + p; aA.x = aA.x * sc + p * f0.x; aA.y = aA.y * sc + p * f0.y; mA = nm;
    nm = fmaxf(mB, y1);
    sc = __expf(mB - nm); p = __expf(y1 - nm);
    sB = sB * sc + p; aB.x = aB.x * sc + p * f1.x; aB.y = aB.y * sc + p * f1.y; mB = nm;
  }
  if (j < dg) {
    int s0 = csr_src[ro + j];
    float2 f0 = unpk2(*(const unsigned*)(fsb + s0 * 128 + 2 * c));
    float x0 = f0.x + fdp.x; x0 = fmaxf(x0, 0.f) + 0.2f * fminf(x0, 0.f);
    float z0 = f0.y + fdp.y; z0 = fmaxf(z0, 0.f) + 0.2f * fminf(z0, 0.f);
    float y0 = rowsum8(ap.x * x0 + ap.y * z0);
    float nm = fmaxf(mA, y0);
    float sc = __expf(mA - nm), p = __expf(y0 - nm);
    sA = sA * sc + p; aA.x = aA.x * sc + p * f0.x; aA.y = aA.y * sc + p * f0.y; mA = nm;
  }
  float ox = 0.f, oy = 0.f;
  if (dg > 0) {
    float M = fmaxf(mA, mB);
    float eA = __expf(mA - M), eB = __expf(mB - M);   // exp(-inf)=0 handles dg==1
    float inv = 1.f / (sA * eA + sB * eB);
    ox = (aA.x * eA + aB.x * eB) * inv;
    oy = (aA.y * eA + aB.y * eB) * inv;
  }
  float2 hv = h2[d * 64 + c];
  float vx = fmaxf(ox + hv.x, 0.f);
  float vy = fmaxf(oy + hv.y, 0.f);
  h2[d * 64 + c] = make_float2(vx, vy);
  if (Ah) {
    ((float2*)buf)[c] = make_float2(vx, vy);
    __syncthreads();
    if (c < 32) {
      int kc = c & 15;
      int off = frag_off(d, kc);
      bf16x8 pk;
      if (c < 16) {
#pragma unroll
        for (int i = 0; i < 8; ++i) pk[i] = (__bf16)buf[kc * 8 + i];
        *(bf16x8*)(Ah + off) = pk;
      } else {
#pragma unroll
        for (int i = 0; i < 8; ++i) {
          float x = buf[kc * 8 + i];
          __bf16 hh = (__bf16)x;
          pk[i] = (__bf16)(x - (float)hh);
        }
        *(bf16x8*)(Al + off) = pk;
      }
    }
  }
}

// ---------------- pooling (n2g sorted: per-graph range + few atomics) ----------------
__global__ __launch_bounds__(128) void pool_kernel(const float* __restrict__ h,
                                                   const int* __restrict__ n2g,
                                                   unsigned* __restrict__ hg)
{
  int g = blockIdx.x >> 3, chunk = blockIdx.x & 7, c = threadIdx.x;
  int lo = 0, hi = NN;
  while (lo < hi) { int mid = (lo + hi) >> 1; if (n2g[mid] < g) lo = mid + 1; else hi = mid; }
  int start = lo;
  hi = NN;
  while (lo < hi) { int mid = (lo + hi) >> 1; if (n2g[mid] < g + 1) lo = mid + 1; else hi = mid; }
  int end = lo;
  int len = end - start;
  int s = start + (int)(((long long)len * chunk) >> 3);
  int e = start + (int)(((long long)len * (chunk + 1)) >> 3);
  float m = 0.f;
  for (int r = s; r < e; ++r) m = fmaxf(m, h[r * 128 + c]);
  atomicMax(&hg[g * 128 + c], __float_as_uint(m));
}

__global__ __launch_bounds__(128) void mlp_kernel(
    const float* __restrict__ hg,
    const float* __restrict__ Wc1, const float* __restrict__ bc1,
    const float* __restrict__ Wc2, const float* __restrict__ bc2,
    const float* __restrict__ Wc3, const float* __restrict__ bc3,
    float* __restrict__ out)
{
  __shared__ float x[128], z1[128], z2[64];
  int g = blockIdx.x, t = threadIdx.x;
  x[t] = hg[g * 128 + t];
  __syncthreads();
  float acc = bc1[t];
  for (int k = 0; k < 128; ++k) acc += x[k] * Wc1[k * 128 + t];
  z1[t] = fmaxf(acc, 0.f);
  __syncthreads();
  if (t < 64) {
    float a2 = bc2[t];
    for (int k = 0; k < 128; ++k) a2 += z1[k] * Wc2[k * 64 + t];
    z2[t] = fmaxf(a2, 0.f);
  }
  __syncthreads();
#pragma unroll
  for (int p = 0; p < 2; ++p) {
    int c = t + p * 128;
    float a3 = bc3[c];
    for (int k = 0; k < 64; ++k) a3 += z2[k] * Wc3[k * 256 + c];
    out[g * 256 + c] = a3;
  }
}

// ---------------- launch ----------------
extern "C" void kernel_launch(void* const* d_in, const int* in_sizes, int n_in,
                              void* d_out, int out_size, void* d_ws, size_t ws_size,
                              hipStream_t stream)
{
  const float* feature = (const float*)d_in[0];
  const float* W_gc1 = (const float*)d_in[1];
  const float* b_gc1 = (const float*)d_in[2];
  const float* W_gc2 = (const float*)d_in[3];
  const float* b_gc2 = (const float*)d_in[4];
  const float* W_src = (const float*)d_in[5];
  const float* b_src = (const float*)d_in[6];
  const float* W_dst = (const float*)d_in[7];
  const float* b_dst = (const float*)d_in[8];
  const float* attn  = (const float*)d_in[9];
  const float* Wc1 = (const float*)d_in[10];
  const float* bc1 = (const float*)d_in[11];
  const float* Wc2 = (const float*)d_in[12];
  const float* bc2 = (const float*)d_in[13];
  const float* Wc3 = (const float*)d_in[14];
  const float* bc3 = (const float*)d_in[15];
  const int* src = (const int*)d_in[16];
  const int* dst = (const int*)d_in[17];
  const int* n2g = (const int*)d_in[18];

  char* base = (char*)d_ws;
  int* indeg  = (int*)base;            base += NN * sizeof(int);
  int* outdeg = (int*)base;            base += NN * sizeof(int);
  int* rowoff = (int*)base;            base += NN * sizeof(int);
  int* cursor = (int*)base;            base += NN * sizeof(int);
  int* bsum   = (int*)base;            base += 256 * sizeof(int);
  int* csr_src = (int*)base;           base += EE * sizeof(int);
  float* ns = (float*)base;            base += NN * sizeof(float);
  float* h0 = (float*)base;            base += (size_t)NN * HIDD * sizeof(float);
  __bf16* fsb = (__bf16*)base;         base += (size_t)NN * HIDD * sizeof(__bf16);
  __bf16* fdb = (__bf16*)base;         base += (size_t)NN * HIDD * sizeof(__bf16);
  __bf16* mb  = (__bf16*)base;         base += (size_t)NN * HIDD * sizeof(__bf16);
  __bf16* Ah = (__bf16*)base;          base += (size_t)RTILES * 2048 * sizeof(__bf16);
  __bf16* Al = (__bf16*)base;          base += (size_t)RTILES * 2048 * sizeof(__bf16);
  __bf16* Wblk = (__bf16*)base;        base += (size_t)8 * 32768 * sizeof(__bf16);
  float* hg = (float*)base;            base += GG * HIDD * sizeof(float);

  // degrees, norms, CSR
  hipMemsetAsync(indeg, 0, 2 * NN * sizeof(int), stream);
  deg_kernel<<<2048, 256, 0, stream>>>(src, dst, outdeg, indeg);
  norm_kernel<<<NBLK, 256, 0, stream>>>(outdeg, ns);
  scan1_kernel<<<NBLK, 256, 0, stream>>>(indeg, rowoff, bsum);
  scan2_kernel<<<1, 256, 0, stream>>>(bsum);
  scan3_kernel<<<NBLK, 256, 0, stream>>>(rowoff, bsum, cursor);
  bin_kernel<<<2048, 256, 0, stream>>>(src, dst, cursor, csr_src);

  // weight split (all 8 matrices)
  split_w_kernel<<<512, 256, 0, stream>>>(W_gc1, W_gc2, W_src, W_dst, Wblk);

  const int split_grid = RTILES * 16 * 16 / 256;

  // GC1: split(feature*ns) -> gemm (bf16 m) -> agg (writes next split, scaled by ns)
  split_h_kernel<<<split_grid, 256, 0, stream>>>(feature, ns, Ah, Al);
  gemm_mfma<<<GEMM_GRID, 256, 0, stream>>>(Ah, Al, Wblk + 0 * 32768, nullptr, mb);
  gc_agg_kernel<<<NN, 64, 0, stream>>>(mb, rowoff, indeg, csr_src,
                                       (const float2*)b_gc1, ns, nullptr, Ah, Al);
  // GC2: gemm (bf16 m) -> agg (writes h0 + unscaled split for GAT1)
  gemm_mfma<<<GEMM_GRID, 256, 0, stream>>>(Ah, Al, Wblk + 1 * 32768, nullptr, mb);
  gc_agg_kernel<<<NN, 64, 0, stream>>>(mb, rowoff, indeg, csr_src,
                                       (const float2*)b_gc2, nullptr, (float2*)h0, Ah, Al);

  // GATv2 x3: fs and fd both bf16
  for (int i = 0; i < 3; ++i) {
    gemm_mfma<<<GEMM_GRID, 256, 0, stream>>>(Ah, Al, Wblk + (2 + i) * 32768, b_src + i * HIDD, fsb);
    gemm_mfma<<<GEMM_GRID, 256, 0, stream>>>(Ah, Al, Wblk + (5 + i) * 32768, b_dst + i * HIDD, fdb);
    bool last = (i == 2);
    gat_node_kernel<<<NN, 64, 0, stream>>>(fsb, fdb,
                                           attn + i * HEADS * DHH,
                                           rowoff, indeg, csr_src, (float2*)h0,
                                           last ? nullptr : Ah, last ? nullptr : Al);
  }

  // pooling + MLP
  hipMemsetAsync(hg, 0, GG * HIDD * sizeof(float), stream);
  pool_kernel<<<GG * 8, 128, 0, stream>>>(h0, n2g, (unsigned*)hg);
  mlp_kernel<<<GG, 128, 0, stream>>>(hg, Wc1, bc1, Wc2, bc2, Wc3, bc3, (float*)d_out);
}

// Round 12
// 443.126 us; speedup vs baseline: 1.6042x; 1.0997x over previous
//
#include <hip/hip_runtime.h>
#include <hip/hip_bf16.h>

#define NN 50000
#define EE 500000
#define GG 64
#define HIDD 128
#define HEADS 8
#define DHH 16
#define NBLK ((NN + 255) / 256)   // 196
#define RTILES 3128               // ceil(50000/16) rowtiles of 16
#define GEMM_GRID 782             // RTILES/4 row-blocks of 64 rows

typedef __bf16 bf16x8 __attribute__((ext_vector_type(8)));
typedef float f32x4 __attribute__((ext_vector_type(4)));

// 8-lane sum reduce, pure DPP: quad xor1, quad xor2, cross-quad (row_half_mirror).
__device__ inline float rowsum8(float y) {
  int t;
  t = __builtin_amdgcn_mov_dpp(__float_as_int(y), 0xB1, 0xF, 0xF, true);  y += __int_as_float(t);
  t = __builtin_amdgcn_mov_dpp(__float_as_int(y), 0x4E, 0xF, 0xF, true);  y += __int_as_float(t);
  t = __builtin_amdgcn_mov_dpp(__float_as_int(y), 0x141, 0xF, 0xF, true); y += __int_as_float(t);
  return y;
}

__device__ inline float2 unpk2(unsigned u) {
  return make_float2(__uint_as_float(u << 16), __uint_as_float(u & 0xFFFF0000u));
}

// blocked bf16 fragment offset for element (row, 8-col-group kc)
__device__ inline int frag_off(int row, int kc) {
  return (row >> 4) * 2048 + (kc >> 2) * 512 + ((row & 15) + (kc & 3) * 16) * 8;
}

// ---------------- degree ----------------
__global__ void deg_kernel(const int* __restrict__ src, const int* __restrict__ dst,
                           int* __restrict__ outdeg, int* __restrict__ indeg) {
  int i = blockIdx.x * blockDim.x + threadIdx.x;
  int stride = gridDim.x * blockDim.x;
  for (; i < EE; i += stride) {
    atomicAdd(&outdeg[src[i]], 1);
    atomicAdd(&indeg[dst[i]], 1);
  }
}

__global__ void norm_kernel(const int* __restrict__ outdeg, float* __restrict__ ns) {
  int i = blockIdx.x * blockDim.x + threadIdx.x;
  if (i < NN) ns[i] = rsqrtf((float)max(outdeg[i], 1));
}

// ---------------- hierarchical exclusive scan ----------------
__global__ __launch_bounds__(256) void scan1_kernel(const int* __restrict__ deg,
                                                    int* __restrict__ excl,
                                                    int* __restrict__ bsum) {
  __shared__ int buf[256];
  int t = threadIdx.x;
  int idx = blockIdx.x * 256 + t;
  int v = (idx < NN) ? deg[idx] : 0;
  buf[t] = v;
  __syncthreads();
#pragma unroll
  for (int off = 1; off < 256; off <<= 1) {
    int tmp = (t >= off) ? buf[t - off] : 0;
    __syncthreads();
    buf[t] += tmp;
    __syncthreads();
  }
  if (idx < NN) excl[idx] = buf[t] - v;
  if (t == 255) bsum[blockIdx.x] = buf[255];
}

__global__ __launch_bounds__(256) void scan2_kernel(int* __restrict__ bsum) {
  __shared__ int buf[256];
  int t = threadIdx.x;
  int v = (t < NBLK) ? bsum[t] : 0;
  buf[t] = v;
  __syncthreads();
#pragma unroll
  for (int off = 1; off < 256; off <<= 1) {
    int tmp = (t >= off) ? buf[t - off] : 0;
    __syncthreads();
    buf[t] += tmp;
    __syncthreads();
  }
  if (t < NBLK) bsum[t] = buf[t] - v;
}

__global__ __launch_bounds__(256) void scan3_kernel(int* __restrict__ excl,
                                                    const int* __restrict__ bsum,
                                                    int* __restrict__ cursor) {
  int idx = blockIdx.x * 256 + threadIdx.x;
  if (idx < NN) {
    int v = excl[idx] + bsum[blockIdx.x];
    excl[idx] = v;
    cursor[idx] = v;
  }
}

__global__ void bin_kernel(const int* __restrict__ src, const int* __restrict__ dst,
                           int* __restrict__ cursor, int* __restrict__ csr_src) {
  int i = blockIdx.x * blockDim.x + threadIdx.x;
  int stride = gridDim.x * blockDim.x;
  for (; i < EE; i += stride) {
    int pos = atomicAdd(&cursor[dst[i]], 1);
    csr_src[pos] = src[i];
  }
}

// ---------------- bf16 hi/lo weight split (transposed, k-blocked, pre-swizzled) ----------------
__global__ __launch_bounds__(256) void split_w_kernel(
    const float* __restrict__ W_gc1, const float* __restrict__ W_gc2,
    const float* __restrict__ W_src, const float* __restrict__ W_dst,
    __bf16* __restrict__ Wblk)
{
  int tid = blockIdx.x * 256 + threadIdx.x;   // 8 * 16384
  int m = tid >> 14;
  int kn = tid & 16383;
  int k = kn >> 7, n = kn & 127;
  const float* Wm = (m == 0) ? W_gc1 : (m == 1) ? W_gc2
                   : (m < 5) ? (W_src + (m - 2) * 16384) : (W_dst + (m - 5) * 16384);
  float v = Wm[kn];
  __bf16 h = (__bf16)v;
  __bf16 l = (__bf16)(v - (float)h);
  int ks = k >> 5;
  int L = n * 32 + ((k >> 3) & 3) * 8 + (k & 7);
  int swz = L ^ ((n & 7) << 3);
  __bf16* dstp = Wblk + m * 32768 + ks * 8192;
  dstp[swz] = h;
  dstp[4096 + swz] = l;
}

// ---------------- bf16 input pack (feature only): single bf16 plane ----------------
__global__ __launch_bounds__(256) void split_h_kernel(
    const float* __restrict__ X, const float* __restrict__ scale,
    __bf16* __restrict__ Ah)
{
  int tid = blockIdx.x * 256 + threadIdx.x;   // RTILES*16*16
  int row = tid >> 4, kc = tid & 15;
  float v[8];
  if (row < NN) {
    const float4* p = (const float4*)(X + row * 128 + kc * 8);
    float4 a = p[0], b = p[1];
    float s = scale ? scale[row] : 1.f;
    v[0] = a.x * s; v[1] = a.y * s; v[2] = a.z * s; v[3] = a.w * s;
    v[4] = b.x * s; v[5] = b.y * s; v[6] = b.z * s; v[7] = b.w * s;
  } else {
#pragma unroll
    for (int i = 0; i < 8; ++i) v[i] = 0.f;
  }
  bf16x8 hi;
#pragma unroll
  for (int i = 0; i < 8; ++i) hi[i] = (__bf16)v[i];
  *(bf16x8*)(Ah + frag_off(row, kc)) = hi;
}

// ---------------- bf16x2 MFMA GEMM: A single bf16, W hi/lo; 64-row blocks ----------------
// acc[2][4] = 32 VGPR, A-read single plane -> low VGPR, high occupancy.
__global__ __launch_bounds__(256) void gemm_mfma(
    const __bf16* __restrict__ Ah,
    const __bf16* __restrict__ Wmat, const float* __restrict__ bias,
    __bf16* __restrict__ outb)
{
  __shared__ __bf16 wt[8192];
  int tid = threadIdx.x;
  int wid = tid >> 6, lane = tid & 63;
  int wr = wid >> 1, wc = wid & 1;       // wr: 32-row half, wc: 64-col half
  int l15 = lane & 15, l4 = lane >> 4;
  f32x4 acc[2][4];
#pragma unroll
  for (int a = 0; a < 2; ++a)
#pragma unroll
    for (int b = 0; b < 4; ++b) acc[a][b] = (f32x4){0.f, 0.f, 0.f, 0.f};
  int rowtile0 = blockIdx.x * 4 + wr * 2;

  for (int ks = 0; ks < 4; ++ks) {
    {
      const bf16x8* g = (const bf16x8*)(Wmat + ks * 8192);
      bf16x8* l = (bf16x8*)wt;
      l[tid]       = g[tid];
      l[tid + 256] = g[tid + 256];
      l[tid + 512] = g[tid + 512];
      l[tid + 768] = g[tid + 768];
    }
    bf16x8 ah[2];
#pragma unroll
    for (int rt = 0; rt < 2; ++rt) {
      int off = (rowtile0 + rt) * 2048 + ks * 512 + lane * 8;
      ah[rt] = *(const bf16x8*)(Ah + off);
    }
    __syncthreads();
#pragma unroll
    for (int ct = 0; ct < 4; ++ct) {
      int n = wc * 64 + ct * 16 + l15;
      int ei = (n * 32 + l4 * 8) ^ ((n & 7) << 3);
      bf16x8 bh = *(const bf16x8*)(wt + ei);
      bf16x8 bl = *(const bf16x8*)(wt + 4096 + ei);
#pragma unroll
      for (int rt = 0; rt < 2; ++rt) {
        acc[rt][ct] = __builtin_amdgcn_mfma_f32_16x16x32_bf16(ah[rt], bh, acc[rt][ct], 0, 0, 0);
        acc[rt][ct] = __builtin_amdgcn_mfma_f32_16x16x32_bf16(ah[rt], bl, acc[rt][ct], 0, 0, 0);
      }
    }
    __syncthreads();
  }
  int rowbase = blockIdx.x * 64 + wr * 32;
#pragma unroll
  for (int ct = 0; ct < 4; ++ct) {
    int col = wc * 64 + ct * 16 + l15;
    float b = bias ? bias[col] : 0.f;
#pragma unroll
    for (int rt = 0; rt < 2; ++rt) {
#pragma unroll
      for (int r = 0; r < 4; ++r) {
        int row = rowbase + rt * 16 + l4 * 4 + r;
        if (row < NN) outb[row * 128 + col] = (__bf16)(acc[rt][ct][r] + b);
      }
    }
  }
}

// ---------------- GraphConv aggregation: bf16 gather, 64 thr/node, x4 unroll ----------------
__global__ __launch_bounds__(64) void gc_agg_kernel(
    const __bf16* __restrict__ mb, const int* __restrict__ rowoff,
    const int* __restrict__ indeg, const int* __restrict__ csr_src,
    const float2* __restrict__ bias2, const float* __restrict__ nsrow,
    float2* __restrict__ out2,        // null = skip fp32 write
    __bf16* __restrict__ Ah)          // null = skip pack
{
  __shared__ float buf[128];
  int d = blockIdx.x, c = threadIdx.x;
  int ro = rowoff[d], dg = indeg[d];
  float2 a0 = {0.f, 0.f}, a1 = {0.f, 0.f}, a2 = {0.f, 0.f}, a3 = {0.f, 0.f};
  int j = 0;
  for (; j + 4 <= dg; j += 4) {
    int s0 = csr_src[ro + j], s1 = csr_src[ro + j + 1];
    int s2 = csr_src[ro + j + 2], s3 = csr_src[ro + j + 3];
    float2 v0 = unpk2(*(const unsigned*)(mb + s0 * 128 + 2 * c));
    float2 v1 = unpk2(*(const unsigned*)(mb + s1 * 128 + 2 * c));
    float2 v2 = unpk2(*(const unsigned*)(mb + s2 * 128 + 2 * c));
    float2 v3 = unpk2(*(const unsigned*)(mb + s3 * 128 + 2 * c));
    a0.x += v0.x; a0.y += v0.y; a1.x += v1.x; a1.y += v1.y;
    a2.x += v2.x; a2.y += v2.y; a3.x += v3.x; a3.y += v3.y;
  }
  for (; j < dg; ++j) {
    float2 v = unpk2(*(const unsigned*)(mb + csr_src[ro + j] * 128 + 2 * c));
    a0.x += v.x; a0.y += v.y;
  }
  float accx = (a0.x + a1.x) + (a2.x + a3.x);
  float accy = (a0.y + a1.y) + (a2.y + a3.y);
  float ndv = rsqrtf((float)max(dg, 1));
  float2 b = bias2[c];
  float vx = fmaxf(accx * ndv + b.x, 0.f);
  float vy = fmaxf(accy * ndv + b.y, 0.f);
  if (out2) out2[d * 64 + c] = make_float2(vx, vy);
  if (Ah) {
    float s = nsrow ? nsrow[d] : 1.f;
    ((float2*)buf)[c] = make_float2(vx * s, vy * s);
    __syncthreads();
    if (c < 16) {
      int off = frag_off(d, c);
      bf16x8 pk;
#pragma unroll
      for (int i = 0; i < 8; ++i) pk[i] = (__bf16)buf[c * 8 + i];
      *(bf16x8*)(Ah + off) = pk;
    }
  }
}

// ---------------- Fused GATv2: bf16 fs gather + bf16 fd, DPP reduce, online softmax ----------------
__global__ __launch_bounds__(64) void gat_node_kernel(
    const __bf16* __restrict__ fsb,   // [N][128] bf16
    const __bf16* __restrict__ fdb,   // [N][128] bf16
    const float* __restrict__ attn,
    const int* __restrict__ rowoff, const int* __restrict__ indeg,
    const int* __restrict__ csr_src,
    float2* __restrict__ h2,          // in/out fp32
    __bf16* __restrict__ Ah)          // null = skip pack
{
  __shared__ float buf[128];
  int d = blockIdx.x, c = threadIdx.x;
  int ro = rowoff[d], dg = indeg[d];
  float2 fdp = unpk2(*(const unsigned*)(fdb + d * 128 + 2 * c));
  float2 ap = ((const float2*)attn)[c];
  float mA = -INFINITY, sA = 0.f; float2 aA = {0.f, 0.f};
  float mB = -INFINITY, sB = 0.f; float2 aB = {0.f, 0.f};
  int j = 0;
  for (; j + 2 <= dg; j += 2) {
    int s0 = csr_src[ro + j], s1 = csr_src[ro + j + 1];
    float2 f0 = unpk2(*(const unsigned*)(fsb + s0 * 128 + 2 * c));
    float2 f1 = unpk2(*(const unsigned*)(fsb + s1 * 128 + 2 * c));
    float x0 = f0.x + fdp.x; x0 = fmaxf(x0, 0.f) + 0.2f * fminf(x0, 0.f);
    float z0 = f0.y + fdp.y; z0 = fmaxf(z0, 0.f) + 0.2f * fminf(z0, 0.f);
    float x1 = f1.x + fdp.x; x1 = fmaxf(x1, 0.f) + 0.2f * fminf(x1, 0.f);
    float z1 = f1.y + fdp.y; z1 = fmaxf(z1, 0.f) + 0.2f * fminf(z1, 0.f);
    float y0 = rowsum8(ap.x * x0 + ap.y * z0);
    float y1 = rowsum8(ap.x * x1 + ap.y * z1);
    float nm = fmaxf(mA, y0);
    float sc = __expf(mA - nm), p = __expf(y0 - nm);
    sA = sA * sc + p; aA.x = aA.x * sc + p * f0.x; aA.y = aA.y * sc + p * f0.y; mA = nm;
    nm = fmaxf(mB, y1);
    sc = __expf(mB - nm); p = __expf(y1 - nm);
    sB = sB * sc + p; aB.x = aB.x * sc + p * f1.x; aB.y = aB.y * sc + p * f1.y; mB = nm;
  }
  if (j < dg) {
    int s0 = csr_src[ro + j];
    float2 f0 = unpk2(*(const unsigned*)(fsb + s0 * 128 + 2 * c));
    float x0 = f0.x + fdp.x; x0 = fmaxf(x0, 0.f) + 0.2f * fminf(x0, 0.f);
    float z0 = f0.y + fdp.y; z0 = fmaxf(z0, 0.f) + 0.2f * fminf(z0, 0.f);
    float y0 = rowsum8(ap.x * x0 + ap.y * z0);
    float nm = fmaxf(mA, y0);
    float sc = __expf(mA - nm), p = __expf(y0 - nm);
    sA = sA * sc + p; aA.x = aA.x * sc + p * f0.x; aA.y = aA.y * sc + p * f0.y; mA = nm;
  }
  float ox = 0.f, oy = 0.f;
  if (dg > 0) {
    float M = fmaxf(mA, mB);
    float eA = __expf(mA - M), eB = __expf(mB - M);   // exp(-inf)=0 handles dg==1
    float inv = 1.f / (sA * eA + sB * eB);
    ox = (aA.x * eA + aB.x * eB) * inv;
    oy = (aA.y * eA + aB.y * eB) * inv;
  }
  float2 hv = h2[d * 64 + c];
  float vx = fmaxf(ox + hv.x, 0.f);
  float vy = fmaxf(oy + hv.y, 0.f);
  h2[d * 64 + c] = make_float2(vx, vy);
  if (Ah) {
    ((float2*)buf)[c] = make_float2(vx, vy);
    __syncthreads();
    if (c < 16) {
      int off = frag_off(d, c);
      bf16x8 pk;
#pragma unroll
      for (int i = 0; i < 8; ++i) pk[i] = (__bf16)buf[c * 8 + i];
      *(bf16x8*)(Ah + off) = pk;
    }
  }
}

// ---------------- pooling (n2g sorted: per-graph range + few atomics) ----------------
__global__ __launch_bounds__(128) void pool_kernel(const float* __restrict__ h,
                                                   const int* __restrict__ n2g,
                                                   unsigned* __restrict__ hg)
{
  int g = blockIdx.x >> 3, chunk = blockIdx.x & 7, c = threadIdx.x;
  int lo = 0, hi = NN;
  while (lo < hi) { int mid = (lo + hi) >> 1; if (n2g[mid] < g) lo = mid + 1; else hi = mid; }
  int start = lo;
  hi = NN;
  while (lo < hi) { int mid = (lo + hi) >> 1; if (n2g[mid] < g + 1) lo = mid + 1; else hi = mid; }
  int end = lo;
  int len = end - start;
  int s = start + (int)(((long long)len * chunk) >> 3);
  int e = start + (int)(((long long)len * (chunk + 1)) >> 3);
  float m = 0.f;
  for (int r = s; r < e; ++r) m = fmaxf(m, h[r * 128 + c]);
  atomicMax(&hg[g * 128 + c], __float_as_uint(m));
}

__global__ __launch_bounds__(128) void mlp_kernel(
    const float* __restrict__ hg,
    const float* __restrict__ Wc1, const float* __restrict__ bc1,
    const float* __restrict__ Wc2, const float* __restrict__ bc2,
    const float* __restrict__ Wc3, const float* __restrict__ bc3,
    float* __restrict__ out)
{
  __shared__ float x[128], z1[128], z2[64];
  int g = blockIdx.x, t = threadIdx.x;
  x[t] = hg[g * 128 + t];
  __syncthreads();
  float acc = bc1[t];
  for (int k = 0; k < 128; ++k) acc += x[k] * Wc1[k * 128 + t];
  z1[t] = fmaxf(acc, 0.f);
  __syncthreads();
  if (t < 64) {
    float a2 = bc2[t];
    for (int k = 0; k < 128; ++k) a2 += z1[k] * Wc2[k * 64 + t];
    z2[t] = fmaxf(a2, 0.f);
  }
  __syncthreads();
#pragma unroll
  for (int p = 0; p < 2; ++p) {
    int c = t + p * 128;
    float a3 = bc3[c];
    for (int k = 0; k < 64; ++k) a3 += z2[k] * Wc3[k * 256 + c];
    out[g * 256 + c] = a3;
  }
}

// ---------------- launch ----------------
extern "C" void kernel_launch(void* const* d_in, const int* in_sizes, int n_in,
                              void* d_out, int out_size, void* d_ws, size_t ws_size,
                              hipStream_t stream)
{
  const float* feature = (const float*)d_in[0];
  const float* W_gc1 = (const float*)d_in[1];
  const float* b_gc1 = (const float*)d_in[2];
  const float* W_gc2 = (const float*)d_in[3];
  const float* b_gc2 = (const float*)d_in[4];
  const float* W_src = (const float*)d_in[5];
  const float* b_src = (const float*)d_in[6];
  const float* W_dst = (const float*)d_in[7];
  const float* b_dst = (const float*)d_in[8];
  const float* attn  = (const float*)d_in[9];
  const float* Wc1 = (const float*)d_in[10];
  const float* bc1 = (const float*)d_in[11];
  const float* Wc2 = (const float*)d_in[12];
  const float* bc2 = (const float*)d_in[13];
  const float* Wc3 = (const float*)d_in[14];
  const float* bc3 = (const float*)d_in[15];
  const int* src = (const int*)d_in[16];
  const int* dst = (const int*)d_in[17];
  const int* n2g = (const int*)d_in[18];

  char* base = (char*)d_ws;
  int* indeg  = (int*)base;            base += NN * sizeof(int);
  int* outdeg = (int*)base;            base += NN * sizeof(int);
  int* rowoff = (int*)base;            base += NN * sizeof(int);
  int* cursor = (int*)base;            base += NN * sizeof(int);
  int* bsum   = (int*)base;            base += 256 * sizeof(int);
  int* csr_src = (int*)base;           base += EE * sizeof(int);
  float* ns = (float*)base;            base += NN * sizeof(float);
  float* h0 = (float*)base;            base += (size_t)NN * HIDD * sizeof(float);
  __bf16* fsb = (__bf16*)base;         base += (size_t)NN * HIDD * sizeof(__bf16);
  __bf16* fdb = (__bf16*)base;         base += (size_t)NN * HIDD * sizeof(__bf16);
  __bf16* mb  = (__bf16*)base;         base += (size_t)NN * HIDD * sizeof(__bf16);
  __bf16* Ah = (__bf16*)base;          base += (size_t)RTILES * 2048 * sizeof(__bf16);
  __bf16* Wblk = (__bf16*)base;        base += (size_t)8 * 32768 * sizeof(__bf16);
  float* hg = (float*)base;            base += GG * HIDD * sizeof(float);

  // degrees, norms, CSR
  hipMemsetAsync(indeg, 0, 2 * NN * sizeof(int), stream);
  deg_kernel<<<2048, 256, 0, stream>>>(src, dst, outdeg, indeg);
  norm_kernel<<<NBLK, 256, 0, stream>>>(outdeg, ns);
  scan1_kernel<<<NBLK, 256, 0, stream>>>(indeg, rowoff, bsum);
  scan2_kernel<<<1, 256, 0, stream>>>(bsum);
  scan3_kernel<<<NBLK, 256, 0, stream>>>(rowoff, bsum, cursor);
  bin_kernel<<<2048, 256, 0, stream>>>(src, dst, cursor, csr_src);

  // weight split (all 8 matrices, hi/lo)
  split_w_kernel<<<512, 256, 0, stream>>>(W_gc1, W_gc2, W_src, W_dst, Wblk);

  const int split_grid = RTILES * 16 * 16 / 256;

  // GC1: pack(feature*ns) -> gemm (bf16 m) -> agg (packs next A, scaled by ns)
  split_h_kernel<<<split_grid, 256, 0, stream>>>(feature, ns, Ah);
  gemm_mfma<<<GEMM_GRID, 256, 0, stream>>>(Ah, Wblk + 0 * 32768, nullptr, mb);
  gc_agg_kernel<<<NN, 64, 0, stream>>>(mb, rowoff, indeg, csr_src,
                                       (const float2*)b_gc1, ns, nullptr, Ah);
  // GC2: gemm (bf16 m) -> agg (writes h0 + unscaled pack for GAT1)
  gemm_mfma<<<GEMM_GRID, 256, 0, stream>>>(Ah, Wblk + 1 * 32768, nullptr, mb);
  gc_agg_kernel<<<NN, 64, 0, stream>>>(mb, rowoff, indeg, csr_src,
                                       (const float2*)b_gc2, nullptr, (float2*)h0, Ah);

  // GATv2 x3: fs and fd both bf16
  for (int i = 0; i < 3; ++i) {
    gemm_mfma<<<GEMM_GRID, 256, 0, stream>>>(Ah, Wblk + (2 + i) * 32768, b_src + i * HIDD, fsb);
    gemm_mfma<<<GEMM_GRID, 256, 0, stream>>>(Ah, Wblk + (5 + i) * 32768, b_dst + i * HIDD, fdb);
    bool last = (i == 2);
    gat_node_kernel<<<NN, 64, 0, stream>>>(fsb, fdb,
                                           attn + i * HEADS * DHH,
                                           rowoff, indeg, csr_src, (float2*)h0,
                                           last ? nullptr : Ah);
  }

  // pooling + MLP
  hipMemsetAsync(hg, 0, GG * HIDD * sizeof(float), stream);
  pool_kernel<<<GG * 8, 128, 0, stream>>>(h0, n2g, (unsigned*)hg);
  mlp_kernel<<<GG, 128, 0, stream>>>(hg, Wc1, bc1, Wc2, bc2, Wc3, bc3, (float*)d_out);
}